// Round 1
// baseline (630.249 us; speedup 1.0000x reference)
//
#include <hip/hip_runtime.h>
#include <hip/hip_bf16.h>

// Problem constants
#define DD 2048
#define SS 10240
#define KK 4096   // 2*DD

typedef __bf16 bf16x8 __attribute__((ext_vector_type(8)));
typedef float  f32x4  __attribute__((ext_vector_type(4)));

__device__ __forceinline__ unsigned short f2bf_rne(float x) {
    unsigned int u = __float_as_uint(x);
    u += 0x7FFFu + ((u >> 16) & 1u);
    return (unsigned short)(u >> 16);
}

// ---------------------------------------------------------------------------
// Prep: W1 [4096][2048] f32 -> W1T [2048][4096] bf16 ; also init s_pre = b2
// grid: (KK/64)*(DD/64) = 64*32 = 2048 blocks x 256 threads
// ---------------------------------------------------------------------------
__global__ __launch_bounds__(256) void prep_kernel(
    const float* __restrict__ W1, const float* __restrict__ b2,
    unsigned short* __restrict__ W1T, float* __restrict__ s_pre) {
    __shared__ float tile[64][65];
    const int t = threadIdx.x;
    const int bf = blockIdx.x % (KK / 64);
    const int bd = blockIdx.x / (KK / 64);
    const int f0 = bf * 64, d0 = bd * 64;

#pragma unroll
    for (int p = 0; p < 4; ++p) {
        int fr = p * 16 + (t >> 4);
        int dc = (t & 15) * 4;
        const float4 v = *(const float4*)&W1[(size_t)(f0 + fr) * DD + d0 + dc];
        tile[fr][dc + 0] = v.x; tile[fr][dc + 1] = v.y;
        tile[fr][dc + 2] = v.z; tile[fr][dc + 3] = v.w;
    }
    __syncthreads();
#pragma unroll
    for (int p = 0; p < 4; ++p) {
        int dr = p * 16 + (t >> 4);     // d index within tile
        int fc = (t & 15) * 4;          // f index within tile
        ushort4 o;
        o.x = f2bf_rne(tile[fc + 0][dr]);
        o.y = f2bf_rne(tile[fc + 1][dr]);
        o.z = f2bf_rne(tile[fc + 2][dr]);
        o.w = f2bf_rne(tile[fc + 3][dr]);
        *(ushort4*)&W1T[(size_t)(d0 + dr) * KK + f0 + fc] = o;
    }
    // init s_pre with b2 (ws is poisoned before every launch)
    int gid = blockIdx.x * 256 + t;
    if (gid < SS) s_pre[gid] = b2[0];
}

// ---------------------------------------------------------------------------
// Fused GEMM: h = relu(sim @ W1 + b1); s_pre[row] += sum_d h[row][d]*W2[d]
// sim[s][k] = k<2048 ? |x0[k]-x1[s][k]| : x0[k-2048]+x1[s][k-2048]  (inline)
// 128x128x32 tile, 4 waves (2x2), mfma_f32_16x16x32_bf16
// grid: (SS/128)*(DD/128) = 80*16 = 1280 blocks x 256 threads
// ---------------------------------------------------------------------------
#define BM 128
#define BN 128
#define BK 32

__global__ __launch_bounds__(256) void gemm_kernel(
    const float* __restrict__ x0, const float* __restrict__ x1,
    const unsigned short* __restrict__ W1T,
    const float* __restrict__ b1, const float* __restrict__ W2,
    float* __restrict__ s_pre) {
    __shared__ unsigned short As[BM][BK];   // m-major, k contiguous
    __shared__ unsigned short Bs[BN][BK];   // n-major, k contiguous

    const int tid  = threadIdx.x;
    const int lane = tid & 63;
    const int wave = tid >> 6;
    const int wr = wave >> 1, wc = wave & 1;
    const int bm = blockIdx.x / (DD / BN);
    const int bn = blockIdx.x % (DD / BN);
    const int m0 = bm * BM, n0 = bn * BN;
    const int lr = lane & 15;
    const int lk = (lane >> 4) * 8;

    f32x4 acc[4][4];
#pragma unroll
    for (int m = 0; m < 4; ++m)
#pragma unroll
        for (int n = 0; n < 4; ++n)
            acc[m][n] = (f32x4){0.f, 0.f, 0.f, 0.f};

    for (int k0 = 0; k0 < KK; k0 += BK) {
        __syncthreads();   // previous iter's LDS reads done

        // --- stage B tile via async global->LDS (2 x 16B per thread) ---
#pragma unroll
        for (int p = 0; p < 2; ++p) {
            int L  = tid + p * 256;               // 0..511
            int n  = L >> 2;
            int k8 = (L & 3) * 8;
            const unsigned short* g = &W1T[(size_t)(n0 + n) * KK + k0 + k8];
            unsigned short* l = &Bs[0][0] + (size_t)L * 8;
            __builtin_amdgcn_global_load_lds(
                (const __attribute__((address_space(1))) void*)g,
                (__attribute__((address_space(3))) void*)l, 16, 0, 0);
        }

        // --- stage A tile: compute sim inline, fp32 -> bf16, ds_write ---
        {
            const int f0 = k0 & (DD - 1);
            const bool second = (k0 >= DD);
            const int fc = (tid & 7) * 4;
            const float4 v0 = *(const float4*)&x0[f0 + fc];
#pragma unroll
            for (int p = 0; p < 4; ++p) {
                int row = p * 32 + (tid >> 3);
                const float4 v1 = *(const float4*)&x1[(size_t)(m0 + row) * DD + f0 + fc];
                ushort4 o;
                o.x = f2bf_rne(second ? (v0.x + v1.x) : fabsf(v0.x - v1.x));
                o.y = f2bf_rne(second ? (v0.y + v1.y) : fabsf(v0.y - v1.y));
                o.z = f2bf_rne(second ? (v0.z + v1.z) : fabsf(v0.z - v1.z));
                o.w = f2bf_rne(second ? (v0.w + v1.w) : fabsf(v0.w - v1.w));
                *(ushort4*)&As[row][fc] = o;
            }
        }
        __syncthreads();   // staging visible (vmcnt+lgkm drained by barrier)

        // --- fragments + 16 MFMAs ---
        bf16x8 a[4], b[4];
#pragma unroll
        for (int m = 0; m < 4; ++m)
            a[m] = *(const bf16x8*)&As[wr * 64 + m * 16 + lr][lk];
#pragma unroll
        for (int n = 0; n < 4; ++n)
            b[n] = *(const bf16x8*)&Bs[wc * 64 + n * 16 + lr][lk];
#pragma unroll
        for (int m = 0; m < 4; ++m)
#pragma unroll
            for (int n = 0; n < 4; ++n)
                acc[m][n] = __builtin_amdgcn_mfma_f32_16x16x32_bf16(
                    a[m], b[n], acc[m][n], 0, 0, 0);
    }

    // --- epilogue: relu(+b1), dot with W2, reduce over cols, atomicAdd ---
    float b1v[4], w2v[4];
#pragma unroll
    for (int n = 0; n < 4; ++n) {
        int col = n0 + wc * 64 + n * 16 + lr;
        b1v[n] = b1[col];
        w2v[n] = W2[col];
    }
#pragma unroll
    for (int m = 0; m < 4; ++m) {
#pragma unroll
        for (int r = 0; r < 4; ++r) {
            float rowsum = 0.f;
#pragma unroll
            for (int n = 0; n < 4; ++n) {
                float v = acc[m][n][r] + b1v[n];
                v = fmaxf(v, 0.f);
                rowsum = fmaf(v, w2v[n], rowsum);
            }
            rowsum += __shfl_xor(rowsum, 1);
            rowsum += __shfl_xor(rowsum, 2);
            rowsum += __shfl_xor(rowsum, 4);
            rowsum += __shfl_xor(rowsum, 8);
            if (lr == 0) {
                int row = m0 + wr * 64 + m * 16 + (lane >> 4) * 4 + r;
                atomicAdd(&s_pre[row], rowsum);
            }
        }
    }
}

// ---------------------------------------------------------------------------
// Chunk-parallel BiLSTM (input=hidden=1). x = sigmoid(s_pre).
// 80 chunks of 128 per direction; 256-step warmup from zero state
// (state contraction <=~0.92/step -> boundary error < 1e-6 << 1e-2 thr).
// ---------------------------------------------------------------------------
#define CHUNK 128
#define WARM  256
#define NCH   (SS / CHUNK)   // 80

__device__ __forceinline__ float sigf(float x) {
    return 1.f / (1.f + __expf(-x));
}
__device__ __forceinline__ float tanhfast(float x) {
    return 2.f / (1.f + __expf(-2.f * x)) - 1.f;
}

__global__ __launch_bounds__(64) void lstm_kernel(
    const float* __restrict__ s_pre,
    const float* __restrict__ Wih_f, const float* __restrict__ Whh_f,
    const float* __restrict__ bih_f, const float* __restrict__ bhh_f,
    const float* __restrict__ Wih_b, const float* __restrict__ Whh_b,
    const float* __restrict__ bih_b, const float* __restrict__ bhh_b,
    float* __restrict__ hf, float* __restrict__ hb) {
    int id = blockIdx.x * blockDim.x + threadIdx.x;
    if (id >= 2 * NCH) return;
    int dir = id / NCH;
    int ch  = id % NCH;
    const float* Wih = dir ? Wih_b : Wih_f;
    const float* Whh = dir ? Whh_b : Whh_f;
    const float* bih = dir ? bih_b : bih_f;
    const float* bhh = dir ? bhh_b : bhh_f;
    const float wi0 = Wih[0], wi1 = Wih[1], wi2 = Wih[2], wi3 = Wih[3];
    const float wh0 = Whh[0], wh1 = Whh[1], wh2 = Whh[2], wh3 = Whh[3];
    const float bb0 = bih[0] + bhh[0], bb1 = bih[1] + bhh[1];
    const float bb2 = bih[2] + bhh[2], bb3 = bih[3] + bhh[3];

    const int pout0 = ch * CHUNK;
    int pstart = pout0 - WARM; if (pstart < 0) pstart = 0;
    const int pend = pout0 + CHUNK;

    float h = 0.f, c = 0.f;
    for (int p = pstart; p < pend; ++p) {
        int s = dir ? (SS - 1 - p) : p;
        float x  = sigf(s_pre[s]);
        float g0 = fmaf(wi0, x, fmaf(wh0, h, bb0));
        float g1 = fmaf(wi1, x, fmaf(wh1, h, bb1));
        float g2 = fmaf(wi2, x, fmaf(wh2, h, bb2));
        float g3 = fmaf(wi3, x, fmaf(wh3, h, bb3));
        float gi = sigf(g0);
        float gf = sigf(g1);
        float gg = tanhfast(g2);
        float go = sigf(g3);
        c = fmaf(gf, c, gi * gg);
        h = go * tanhfast(c);
        if (p >= pout0) {
            if (dir) hb[s] = h; else hf[s] = h;
        }
    }
}

// ---------------------------------------------------------------------------
// Head: out[j] = sigmoid( sum_{i<5} hf[5j+i]*W3[2i] + hb[5j+i]*W3[2i+1] + b3 )
// ---------------------------------------------------------------------------
__global__ __launch_bounds__(256) void final_kernel(
    const float* __restrict__ hf, const float* __restrict__ hb,
    const float* __restrict__ W3, const float* __restrict__ b3,
    float* __restrict__ out) {
    int j = blockIdx.x * blockDim.x + threadIdx.x;
    if (j >= (SS * 2) / 10) return;   // 2048
    float acc = b3[0];
#pragma unroll
    for (int i = 0; i < 5; ++i) {
        acc = fmaf(hf[5 * j + i], W3[2 * i],     acc);
        acc = fmaf(hb[5 * j + i], W3[2 * i + 1], acc);
    }
    out[j] = sigf(acc);
}

// ---------------------------------------------------------------------------
extern "C" void kernel_launch(void* const* d_in, const int* in_sizes, int n_in,
                              void* d_out, int out_size, void* d_ws, size_t ws_size,
                              hipStream_t stream) {
    const float* x0    = (const float*)d_in[0];
    const float* x1    = (const float*)d_in[1];
    const float* W1    = (const float*)d_in[2];
    const float* b1    = (const float*)d_in[3];
    const float* W2    = (const float*)d_in[4];
    const float* b2    = (const float*)d_in[5];
    const float* Wih_f = (const float*)d_in[6];
    const float* Whh_f = (const float*)d_in[7];
    const float* bih_f = (const float*)d_in[8];
    const float* bhh_f = (const float*)d_in[9];
    const float* Wih_b = (const float*)d_in[10];
    const float* Whh_b = (const float*)d_in[11];
    const float* bih_b = (const float*)d_in[12];
    const float* bhh_b = (const float*)d_in[13];
    const float* W3    = (const float*)d_in[14];
    const float* b3    = (const float*)d_in[15];
    float* out = (float*)d_out;

    char* ws = (char*)d_ws;
    unsigned short* W1T = (unsigned short*)ws;                       // 16 MB
    float* s_pre = (float*)(ws + (size_t)KK * DD * 2);               // 40 KB
    float* hf    = s_pre + SS;
    float* hb    = hf + SS;

    prep_kernel<<<(KK / 64) * (DD / 64), 256, 0, stream>>>(W1, b2, W1T, s_pre);
    gemm_kernel<<<(SS / BM) * (DD / BN), 256, 0, stream>>>(x0, x1, W1T, b1, W2, s_pre);
    lstm_kernel<<<(2 * NCH + 63) / 64, 64, 0, stream>>>(
        s_pre, Wih_f, Whh_f, bih_f, bhh_f, Wih_b, Whh_b, bih_b, bhh_b, hf, hb);
    final_kernel<<<((SS * 2) / 10 + 255) / 256, 256, 0, stream>>>(hf, hb, W3, b3, out);
}

// Round 2
// 538.471 us; speedup vs baseline: 1.1704x; 1.1704x over previous
//
#include <hip/hip_runtime.h>
#include <hip/hip_bf16.h>

// Problem constants
#define DD 2048
#define SS 10240
#define KK 4096   // 2*DD

typedef __bf16 bf16x8 __attribute__((ext_vector_type(8)));
typedef float  f32x4  __attribute__((ext_vector_type(4)));

__device__ __forceinline__ unsigned short f2bf_rne(float x) {
    unsigned int u = __float_as_uint(x);
    u += 0x7FFFu + ((u >> 16) & 1u);
    return (unsigned short)(u >> 16);
}

// ---------------------------------------------------------------------------
// Prep: W1 [4096][2048] f32 -> W1T [2048][4096] bf16 ; also init s_pre = b2
// grid: (KK/64)*(DD/64) = 64*32 = 2048 blocks x 256 threads
// ---------------------------------------------------------------------------
__global__ __launch_bounds__(256) void prep_kernel(
    const float* __restrict__ W1, const float* __restrict__ b2,
    unsigned short* __restrict__ W1T, float* __restrict__ s_pre) {
    __shared__ float tile[64][65];
    const int t = threadIdx.x;
    const int bf = blockIdx.x % (KK / 64);
    const int bd = blockIdx.x / (KK / 64);
    const int f0 = bf * 64, d0 = bd * 64;

#pragma unroll
    for (int p = 0; p < 4; ++p) {
        int fr = p * 16 + (t >> 4);
        int dc = (t & 15) * 4;
        const float4 v = *(const float4*)&W1[(size_t)(f0 + fr) * DD + d0 + dc];
        tile[fr][dc + 0] = v.x; tile[fr][dc + 1] = v.y;
        tile[fr][dc + 2] = v.z; tile[fr][dc + 3] = v.w;
    }
    __syncthreads();
#pragma unroll
    for (int p = 0; p < 4; ++p) {
        int dr = p * 16 + (t >> 4);     // d index within tile
        int fc = (t & 15) * 4;          // f index within tile
        ushort4 o;
        o.x = f2bf_rne(tile[fc + 0][dr]);
        o.y = f2bf_rne(tile[fc + 1][dr]);
        o.z = f2bf_rne(tile[fc + 2][dr]);
        o.w = f2bf_rne(tile[fc + 3][dr]);
        *(ushort4*)&W1T[(size_t)(d0 + dr) * KK + f0 + fc] = o;
    }
    // init s_pre with b2 (ws is poisoned before every launch)
    int gid = blockIdx.x * 256 + t;
    if (gid < SS) s_pre[gid] = b2[0];
}

// ---------------------------------------------------------------------------
// Sim materialization: sim[s][k] bf16, k<2048: |x0[k]-x1[s][k]|,
// k>=2048: x0[k-2048]+x1[s][k-2048]. One pass over x1.
// Each thread: 8 d-indices -> 16B write to each half.
// grid: SS blocks x 256 threads  (256*8 = 2048 = DD per block-row)
// ---------------------------------------------------------------------------
__global__ __launch_bounds__(256) void sim_kernel(
    const float* __restrict__ x0, const float* __restrict__ x1,
    unsigned short* __restrict__ simB) {
    const int s = blockIdx.x;
    const int d = threadIdx.x * 8;
    const float4 a0 = *(const float4*)&x0[d];
    const float4 a1 = *(const float4*)&x0[d + 4];
    const float4 v0 = *(const float4*)&x1[(size_t)s * DD + d];
    const float4 v1 = *(const float4*)&x1[(size_t)s * DD + d + 4];
    ushort4 lo0, lo1, hi0, hi1;
    lo0.x = f2bf_rne(fabsf(a0.x - v0.x)); hi0.x = f2bf_rne(a0.x + v0.x);
    lo0.y = f2bf_rne(fabsf(a0.y - v0.y)); hi0.y = f2bf_rne(a0.y + v0.y);
    lo0.z = f2bf_rne(fabsf(a0.z - v0.z)); hi0.z = f2bf_rne(a0.z + v0.z);
    lo0.w = f2bf_rne(fabsf(a0.w - v0.w)); hi0.w = f2bf_rne(a0.w + v0.w);
    lo1.x = f2bf_rne(fabsf(a1.x - v1.x)); hi1.x = f2bf_rne(a1.x + v1.x);
    lo1.y = f2bf_rne(fabsf(a1.y - v1.y)); hi1.y = f2bf_rne(a1.y + v1.y);
    lo1.z = f2bf_rne(fabsf(a1.z - v1.z)); hi1.z = f2bf_rne(a1.z + v1.z);
    lo1.w = f2bf_rne(fabsf(a1.w - v1.w)); hi1.w = f2bf_rne(a1.w + v1.w);
    unsigned short* row = &simB[(size_t)s * KK];
    *(ushort4*)&row[d]          = lo0;
    *(ushort4*)&row[d + 4]      = lo1;
    *(ushort4*)&row[DD + d]     = hi0;
    *(ushort4*)&row[DD + d + 4] = hi1;
}

// ---------------------------------------------------------------------------
// GEMM (m97 structure): h = relu(sim @ W1 + b1); s_pre[row] += h . W2
// A = simB [S][K] bf16 (k-contig), B = W1T [N][K] bf16 (k-contig).
// 128x128x32 tile, 4 waves (2x2), mfma_f32_16x16x32_bf16,
// both tiles staged with global_load_lds width=16.
// grid: (SS/128)*(DD/128) = 80*16 = 1280 blocks x 256 threads
// ---------------------------------------------------------------------------
#define BM 128
#define BN 128
#define BK 32

__global__ __launch_bounds__(256) void gemm2_kernel(
    const unsigned short* __restrict__ simB,
    const unsigned short* __restrict__ W1T,
    const float* __restrict__ b1, const float* __restrict__ W2,
    float* __restrict__ s_pre) {
    __shared__ unsigned short As[BM][BK];   // m-major, k contiguous
    __shared__ unsigned short Bs[BN][BK];   // n-major, k contiguous

    const int tid  = threadIdx.x;
    const int lane = tid & 63;
    const int wave = tid >> 6;
    const int wr = wave >> 1, wc = wave & 1;
    const int bm = blockIdx.x / (DD / BN);
    const int bn = blockIdx.x % (DD / BN);
    const int m0 = bm * BM, n0 = bn * BN;
    const int lr = lane & 15;
    const int lk = (lane >> 4) * 8;

    f32x4 acc[4][4];
#pragma unroll
    for (int m = 0; m < 4; ++m)
#pragma unroll
        for (int n = 0; n < 4; ++n)
            acc[m][n] = (f32x4){0.f, 0.f, 0.f, 0.f};

    // per-thread staging addresses (L = tid + p*256)
    const int rowL = tid >> 2;          // 0..63
    const int k8L  = (tid & 3) * 8;
    const unsigned short* gA0 = &simB[(size_t)(m0 + rowL) * KK + k8L];
    const unsigned short* gA1 = &simB[(size_t)(m0 + 64 + rowL) * KK + k8L];
    const unsigned short* gB0 = &W1T[(size_t)(n0 + rowL) * KK + k8L];
    const unsigned short* gB1 = &W1T[(size_t)(n0 + 64 + rowL) * KK + k8L];
    unsigned short* lA0 = &As[0][0] + (size_t)tid * 8;
    unsigned short* lA1 = &As[0][0] + (size_t)(tid + 256) * 8;
    unsigned short* lB0 = &Bs[0][0] + (size_t)tid * 8;
    unsigned short* lB1 = &Bs[0][0] + (size_t)(tid + 256) * 8;

    for (int k0 = 0; k0 < KK; k0 += BK) {
        __syncthreads();   // previous iter's LDS reads done
        __builtin_amdgcn_global_load_lds(
            (const __attribute__((address_space(1))) void*)(gA0 + k0),
            (__attribute__((address_space(3))) void*)lA0, 16, 0, 0);
        __builtin_amdgcn_global_load_lds(
            (const __attribute__((address_space(1))) void*)(gA1 + k0),
            (__attribute__((address_space(3))) void*)lA1, 16, 0, 0);
        __builtin_amdgcn_global_load_lds(
            (const __attribute__((address_space(1))) void*)(gB0 + k0),
            (__attribute__((address_space(3))) void*)lB0, 16, 0, 0);
        __builtin_amdgcn_global_load_lds(
            (const __attribute__((address_space(1))) void*)(gB1 + k0),
            (__attribute__((address_space(3))) void*)lB1, 16, 0, 0);
        __syncthreads();   // staging visible (vmcnt drained before barrier)

        bf16x8 a[4], b[4];
#pragma unroll
        for (int m = 0; m < 4; ++m)
            a[m] = *(const bf16x8*)&As[wr * 64 + m * 16 + lr][lk];
#pragma unroll
        for (int n = 0; n < 4; ++n)
            b[n] = *(const bf16x8*)&Bs[wc * 64 + n * 16 + lr][lk];
#pragma unroll
        for (int m = 0; m < 4; ++m)
#pragma unroll
            for (int n = 0; n < 4; ++n)
                acc[m][n] = __builtin_amdgcn_mfma_f32_16x16x32_bf16(
                    a[m], b[n], acc[m][n], 0, 0, 0);
    }

    // --- epilogue: relu(+b1), dot with W2, reduce over cols, atomicAdd ---
    float b1v[4], w2v[4];
#pragma unroll
    for (int n = 0; n < 4; ++n) {
        int col = n0 + wc * 64 + n * 16 + lr;
        b1v[n] = b1[col];
        w2v[n] = W2[col];
    }
#pragma unroll
    for (int m = 0; m < 4; ++m) {
#pragma unroll
        for (int r = 0; r < 4; ++r) {
            float rowsum = 0.f;
#pragma unroll
            for (int n = 0; n < 4; ++n) {
                float v = acc[m][n][r] + b1v[n];
                v = fmaxf(v, 0.f);
                rowsum = fmaf(v, w2v[n], rowsum);
            }
            rowsum += __shfl_xor(rowsum, 1);
            rowsum += __shfl_xor(rowsum, 2);
            rowsum += __shfl_xor(rowsum, 4);
            rowsum += __shfl_xor(rowsum, 8);
            if (lr == 0) {
                int row = m0 + wr * 64 + m * 16 + (lane >> 4) * 4 + r;
                atomicAdd(&s_pre[row], rowsum);
            }
        }
    }
}

// ---------------------------------------------------------------------------
// Fallback GEMM (inline sim staging) — used only if ws too small for simB.
// ---------------------------------------------------------------------------
__global__ __launch_bounds__(256) void gemm_kernel(
    const float* __restrict__ x0, const float* __restrict__ x1,
    const unsigned short* __restrict__ W1T,
    const float* __restrict__ b1, const float* __restrict__ W2,
    float* __restrict__ s_pre) {
    __shared__ unsigned short As[BM][BK];
    __shared__ unsigned short Bs[BN][BK];

    const int tid  = threadIdx.x;
    const int lane = tid & 63;
    const int wave = tid >> 6;
    const int wr = wave >> 1, wc = wave & 1;
    const int bm = blockIdx.x / (DD / BN);
    const int bn = blockIdx.x % (DD / BN);
    const int m0 = bm * BM, n0 = bn * BN;
    const int lr = lane & 15;
    const int lk = (lane >> 4) * 8;

    f32x4 acc[4][4];
#pragma unroll
    for (int m = 0; m < 4; ++m)
#pragma unroll
        for (int n = 0; n < 4; ++n)
            acc[m][n] = (f32x4){0.f, 0.f, 0.f, 0.f};

    for (int k0 = 0; k0 < KK; k0 += BK) {
        __syncthreads();
#pragma unroll
        for (int p = 0; p < 2; ++p) {
            int L  = tid + p * 256;
            int n  = L >> 2;
            int k8 = (L & 3) * 8;
            const unsigned short* g = &W1T[(size_t)(n0 + n) * KK + k0 + k8];
            unsigned short* l = &Bs[0][0] + (size_t)L * 8;
            __builtin_amdgcn_global_load_lds(
                (const __attribute__((address_space(1))) void*)g,
                (__attribute__((address_space(3))) void*)l, 16, 0, 0);
        }
        {
            const int f0 = k0 & (DD - 1);
            const bool second = (k0 >= DD);
            const int fc = (tid & 7) * 4;
            const float4 v0 = *(const float4*)&x0[f0 + fc];
#pragma unroll
            for (int p = 0; p < 4; ++p) {
                int row = p * 32 + (tid >> 3);
                const float4 v1 = *(const float4*)&x1[(size_t)(m0 + row) * DD + f0 + fc];
                ushort4 o;
                o.x = f2bf_rne(second ? (v0.x + v1.x) : fabsf(v0.x - v1.x));
                o.y = f2bf_rne(second ? (v0.y + v1.y) : fabsf(v0.y - v1.y));
                o.z = f2bf_rne(second ? (v0.z + v1.z) : fabsf(v0.z - v1.z));
                o.w = f2bf_rne(second ? (v0.w + v1.w) : fabsf(v0.w - v1.w));
                *(ushort4*)&As[row][fc] = o;
            }
        }
        __syncthreads();

        bf16x8 a[4], b[4];
#pragma unroll
        for (int m = 0; m < 4; ++m)
            a[m] = *(const bf16x8*)&As[wr * 64 + m * 16 + lr][lk];
#pragma unroll
        for (int n = 0; n < 4; ++n)
            b[n] = *(const bf16x8*)&Bs[wc * 64 + n * 16 + lr][lk];
#pragma unroll
        for (int m = 0; m < 4; ++m)
#pragma unroll
            for (int n = 0; n < 4; ++n)
                acc[m][n] = __builtin_amdgcn_mfma_f32_16x16x32_bf16(
                    a[m], b[n], acc[m][n], 0, 0, 0);
    }

    float b1v[4], w2v[4];
#pragma unroll
    for (int n = 0; n < 4; ++n) {
        int col = n0 + wc * 64 + n * 16 + lr;
        b1v[n] = b1[col];
        w2v[n] = W2[col];
    }
#pragma unroll
    for (int m = 0; m < 4; ++m) {
#pragma unroll
        for (int r = 0; r < 4; ++r) {
            float rowsum = 0.f;
#pragma unroll
            for (int n = 0; n < 4; ++n) {
                float v = acc[m][n][r] + b1v[n];
                v = fmaxf(v, 0.f);
                rowsum = fmaf(v, w2v[n], rowsum);
            }
            rowsum += __shfl_xor(rowsum, 1);
            rowsum += __shfl_xor(rowsum, 2);
            rowsum += __shfl_xor(rowsum, 4);
            rowsum += __shfl_xor(rowsum, 8);
            if (lr == 0) {
                int row = m0 + wr * 64 + m * 16 + (lane >> 4) * 4 + r;
                atomicAdd(&s_pre[row], rowsum);
            }
        }
    }
}

// ---------------------------------------------------------------------------
// Chunk-parallel BiLSTM (input=hidden=1). x = sigmoid(s_pre).
// 80 chunks of 128 per direction; 256-step warmup from zero state.
// ---------------------------------------------------------------------------
#define CHUNK 128
#define WARM  256
#define NCH   (SS / CHUNK)   // 80

__device__ __forceinline__ float sigf(float x) {
    return 1.f / (1.f + __expf(-x));
}
__device__ __forceinline__ float tanhfast(float x) {
    return 2.f / (1.f + __expf(-2.f * x)) - 1.f;
}

__global__ __launch_bounds__(64) void lstm_kernel(
    const float* __restrict__ s_pre,
    const float* __restrict__ Wih_f, const float* __restrict__ Whh_f,
    const float* __restrict__ bih_f, const float* __restrict__ bhh_f,
    const float* __restrict__ Wih_b, const float* __restrict__ Whh_b,
    const float* __restrict__ bih_b, const float* __restrict__ bhh_b,
    float* __restrict__ hf, float* __restrict__ hb) {
    int id = blockIdx.x * blockDim.x + threadIdx.x;
    if (id >= 2 * NCH) return;
    int dir = id / NCH;
    int ch  = id % NCH;
    const float* Wih = dir ? Wih_b : Wih_f;
    const float* Whh = dir ? Whh_b : Whh_f;
    const float* bih = dir ? bih_b : bih_f;
    const float* bhh = dir ? bhh_b : bhh_f;
    const float wi0 = Wih[0], wi1 = Wih[1], wi2 = Wih[2], wi3 = Wih[3];
    const float wh0 = Whh[0], wh1 = Whh[1], wh2 = Whh[2], wh3 = Whh[3];
    const float bb0 = bih[0] + bhh[0], bb1 = bih[1] + bhh[1];
    const float bb2 = bih[2] + bhh[2], bb3 = bih[3] + bhh[3];

    const int pout0 = ch * CHUNK;
    int pstart = pout0 - WARM; if (pstart < 0) pstart = 0;
    const int pend = pout0 + CHUNK;

    float h = 0.f, c = 0.f;
    for (int p = pstart; p < pend; ++p) {
        int s = dir ? (SS - 1 - p) : p;
        float x  = sigf(s_pre[s]);
        float g0 = fmaf(wi0, x, fmaf(wh0, h, bb0));
        float g1 = fmaf(wi1, x, fmaf(wh1, h, bb1));
        float g2 = fmaf(wi2, x, fmaf(wh2, h, bb2));
        float g3 = fmaf(wi3, x, fmaf(wh3, h, bb3));
        float gi = sigf(g0);
        float gf = sigf(g1);
        float gg = tanhfast(g2);
        float go = sigf(g3);
        c = fmaf(gf, c, gi * gg);
        h = go * tanhfast(c);
        if (p >= pout0) {
            if (dir) hb[s] = h; else hf[s] = h;
        }
    }
}

// ---------------------------------------------------------------------------
// Head: out[j] = sigmoid( sum_{i<5} hf[5j+i]*W3[2i] + hb[5j+i]*W3[2i+1] + b3 )
// ---------------------------------------------------------------------------
__global__ __launch_bounds__(256) void final_kernel(
    const float* __restrict__ hf, const float* __restrict__ hb,
    const float* __restrict__ W3, const float* __restrict__ b3,
    float* __restrict__ out) {
    int j = blockIdx.x * blockDim.x + threadIdx.x;
    if (j >= (SS * 2) / 10) return;   // 2048
    float acc = b3[0];
#pragma unroll
    for (int i = 0; i < 5; ++i) {
        acc = fmaf(hf[5 * j + i], W3[2 * i],     acc);
        acc = fmaf(hb[5 * j + i], W3[2 * i + 1], acc);
    }
    out[j] = sigf(acc);
}

// ---------------------------------------------------------------------------
extern "C" void kernel_launch(void* const* d_in, const int* in_sizes, int n_in,
                              void* d_out, int out_size, void* d_ws, size_t ws_size,
                              hipStream_t stream) {
    const float* x0    = (const float*)d_in[0];
    const float* x1    = (const float*)d_in[1];
    const float* W1    = (const float*)d_in[2];
    const float* b1    = (const float*)d_in[3];
    const float* W2    = (const float*)d_in[4];
    const float* b2    = (const float*)d_in[5];
    const float* Wih_f = (const float*)d_in[6];
    const float* Whh_f = (const float*)d_in[7];
    const float* bih_f = (const float*)d_in[8];
    const float* bhh_f = (const float*)d_in[9];
    const float* Wih_b = (const float*)d_in[10];
    const float* Whh_b = (const float*)d_in[11];
    const float* bih_b = (const float*)d_in[12];
    const float* bhh_b = (const float*)d_in[13];
    const float* W3    = (const float*)d_in[14];
    const float* b3    = (const float*)d_in[15];
    float* out = (float*)d_out;

    char* ws = (char*)d_ws;
    const size_t w1t_bytes = (size_t)KK * DD * 2;        // 16 MB
    unsigned short* W1T = (unsigned short*)ws;
    float* s_pre = (float*)(ws + w1t_bytes);             // 40 KB
    float* hf    = s_pre + SS;
    float* hb    = hf + SS;
    size_t off_sim = w1t_bytes + 3 * (size_t)SS * 4;
    off_sim = (off_sim + 255) & ~(size_t)255;
    unsigned short* simB = (unsigned short*)(ws + off_sim);
    const size_t need = off_sim + (size_t)SS * KK * 2;   // ~100.8 MB

    prep_kernel<<<(KK / 64) * (DD / 64), 256, 0, stream>>>(W1, b2, W1T, s_pre);
    if (ws_size >= need) {
        sim_kernel<<<SS, 256, 0, stream>>>(x0, x1, simB);
        gemm2_kernel<<<(SS / BM) * (DD / BN), 256, 0, stream>>>(
            simB, W1T, b1, W2, s_pre);
    } else {
        gemm_kernel<<<(SS / BM) * (DD / BN), 256, 0, stream>>>(
            x0, x1, W1T, b1, W2, s_pre);
    }
    lstm_kernel<<<(2 * NCH + 63) / 64, 64, 0, stream>>>(
        s_pre, Wih_f, Whh_f, bih_f, bhh_f, Wih_b, Whh_b, bih_b, bhh_b, hf, hb);
    final_kernel<<<((SS * 2) / 10 + 255) / 256, 256, 0, stream>>>(hf, hb, W3, b3, out);
}

// Round 4
// 415.900 us; speedup vs baseline: 1.5154x; 1.2947x over previous
//
#include <hip/hip_runtime.h>
#include <hip/hip_bf16.h>

// Problem constants
#define DD 2048
#define SS 10240
#define KK 4096   // 2*DD

typedef __bf16 bf16x8 __attribute__((ext_vector_type(8)));
typedef float  f32x4  __attribute__((ext_vector_type(4)));

__device__ __forceinline__ unsigned short f2bf_rne(float x) {
    unsigned int u = __float_as_uint(x);
    u += 0x7FFFu + ((u >> 16) & 1u);
    return (unsigned short)(u >> 16);
}

// ---------------------------------------------------------------------------
// Prep: W1 [4096][2048] f32 -> W1T [2048][4096] bf16 ; also init s_pre = b2
// ---------------------------------------------------------------------------
__global__ __launch_bounds__(256) void prep_kernel(
    const float* __restrict__ W1, const float* __restrict__ b2,
    unsigned short* __restrict__ W1T, float* __restrict__ s_pre) {
    __shared__ float tile[64][65];
    const int t = threadIdx.x;
    const int bf = blockIdx.x % (KK / 64);
    const int bd = blockIdx.x / (KK / 64);
    const int f0 = bf * 64, d0 = bd * 64;

#pragma unroll
    for (int p = 0; p < 4; ++p) {
        int fr = p * 16 + (t >> 4);
        int dc = (t & 15) * 4;
        const float4 v = *(const float4*)&W1[(size_t)(f0 + fr) * DD + d0 + dc];
        tile[fr][dc + 0] = v.x; tile[fr][dc + 1] = v.y;
        tile[fr][dc + 2] = v.z; tile[fr][dc + 3] = v.w;
    }
    __syncthreads();
#pragma unroll
    for (int p = 0; p < 4; ++p) {
        int dr = p * 16 + (t >> 4);
        int fc = (t & 15) * 4;
        ushort4 o;
        o.x = f2bf_rne(tile[fc + 0][dr]);
        o.y = f2bf_rne(tile[fc + 1][dr]);
        o.z = f2bf_rne(tile[fc + 2][dr]);
        o.w = f2bf_rne(tile[fc + 3][dr]);
        *(ushort4*)&W1T[(size_t)(d0 + dr) * KK + f0 + fc] = o;
    }
    int gid = blockIdx.x * 256 + t;
    if (gid < SS) s_pre[gid] = b2[0];
}

// ---------------------------------------------------------------------------
// Sim materialization: sim[s][k] bf16 row-major [SS][KK].
// ---------------------------------------------------------------------------
__global__ __launch_bounds__(256) void sim_kernel(
    const float* __restrict__ x0, const float* __restrict__ x1,
    unsigned short* __restrict__ simB) {
    const int s = blockIdx.x;
    const int d = threadIdx.x * 8;
    const float4 a0 = *(const float4*)&x0[d];
    const float4 a1 = *(const float4*)&x0[d + 4];
    const float4 v0 = *(const float4*)&x1[(size_t)s * DD + d];
    const float4 v1 = *(const float4*)&x1[(size_t)s * DD + d + 4];
    ushort4 lo0, lo1, hi0, hi1;
    lo0.x = f2bf_rne(fabsf(a0.x - v0.x)); hi0.x = f2bf_rne(a0.x + v0.x);
    lo0.y = f2bf_rne(fabsf(a0.y - v0.y)); hi0.y = f2bf_rne(a0.y + v0.y);
    lo0.z = f2bf_rne(fabsf(a0.z - v0.z)); hi0.z = f2bf_rne(a0.z + v0.z);
    lo0.w = f2bf_rne(fabsf(a0.w - v0.w)); hi0.w = f2bf_rne(a0.w + v0.w);
    lo1.x = f2bf_rne(fabsf(a1.x - v1.x)); hi1.x = f2bf_rne(a1.x + v1.x);
    lo1.y = f2bf_rne(fabsf(a1.y - v1.y)); hi1.y = f2bf_rne(a1.y + v1.y);
    lo1.z = f2bf_rne(fabsf(a1.z - v1.z)); hi1.z = f2bf_rne(a1.z + v1.z);
    lo1.w = f2bf_rne(fabsf(a1.w - v1.w)); hi1.w = f2bf_rne(a1.w + v1.w);
    unsigned short* row = &simB[(size_t)s * KK];
    *(ushort4*)&row[d]          = lo0;
    *(ushort4*)&row[d + 4]      = lo1;
    *(ushort4*)&row[DD + d]     = hi0;
    *(ushort4*)&row[DD + d + 4] = hi1;
}

// ---------------------------------------------------------------------------
// gemm3: 320x256 tile, BK=64, 512 thr (8 waves 4x2, wave out 80x128).
// Counted-vmcnt double-buffer pipeline (no __syncthreads, no vmcnt(0) in
// steady loop). T2 XOR swizzle: LDS[row][slot] holds global granule
// slot^(row&7); staged linearly via pre-swizzled global source (rule #21).
// grid: 32*8 = 256 blocks exactly (1/CU). bn = blockIdx&7 -> XCD-pinned.
// ---------------------------------------------------------------------------
#define BM3 320
#define BN3 256
#define BK3 64
#define NKT (KK / BK3)   // 64

// stage A: 5 rounds x 512 thr x 16B = 40 KB (320 rows x 128 B)
#define STAGE_A(ktv, BUFV)                                                     \
    _Pragma("unroll")                                                          \
    for (int L = 0; L < 5; ++L) {                                              \
        __builtin_amdgcn_global_load_lds(                                      \
            (const __attribute__((address_space(1))) void*)(gA + (size_t)L * 64 * KK + (size_t)(ktv) * 64), \
            (__attribute__((address_space(3))) void*)&lds[BUFV][t * 8 + L * 4096], \
            16, 0, 0);                                                         \
    }
// stage B: 4 rounds = 32 KB (256 rows x 128 B)
#define STAGE_B(ktv, BUFV)                                                     \
    _Pragma("unroll")                                                          \
    for (int L = 0; L < 4; ++L) {                                              \
        __builtin_amdgcn_global_load_lds(                                      \
            (const __attribute__((address_space(1))) void*)(gB + (size_t)L * 64 * KK + (size_t)(ktv) * 64), \
            (__attribute__((address_space(3))) void*)&lds[BUFV][20480 + t * 8 + L * 4096], \
            16, 0, 0);                                                         \
    }

// B-frags loaded in two halves of 4 (VGPR headroom: avoid in-loop spill,
// which would add scratch vmem ops and corrupt the counted vmcnt waits).
#define BODY(ktv, BUF, SA_LIT, SB_LIT, DO_STAGE)                               \
    {                                                                          \
        asm volatile("s_waitcnt vmcnt(" SA_LIT ")" ::: "memory");              \
        __builtin_amdgcn_s_barrier();                                          \
        __builtin_amdgcn_sched_barrier(0);                                     \
        if (DO_STAGE) { STAGE_A((ktv) + 1, BUF ^ 1) }                          \
        asm volatile("s_waitcnt vmcnt(" SB_LIT ")" ::: "memory");              \
        __builtin_amdgcn_s_barrier();                                          \
        __builtin_amdgcn_sched_barrier(0);                                     \
        if (DO_STAGE) { STAGE_B((ktv) + 1, BUF ^ 1) }                          \
        _Pragma("unroll")                                                      \
        for (int ks = 0; ks < 2; ++ks) {                                       \
            const int gx = ks ? gx1 : gx0;                                     \
            _Pragma("unroll")                                                  \
            for (int h = 0; h < 2; ++h) {                                      \
                bf16x8 bfr[4];                                                 \
                _Pragma("unroll")                                              \
                for (int n = 0; n < 4; ++n)                                    \
                    bfr[n] = *(const bf16x8*)&lds[BUF][boff + (h * 4 + n) * 1024 + gx]; \
                _Pragma("unroll")                                              \
                for (int m = 0; m < 5; ++m) {                                  \
                    bf16x8 afr = *(const bf16x8*)&lds[BUF][aoff + m * 1024 + gx]; \
                    __builtin_amdgcn_s_setprio(1);                             \
                    _Pragma("unroll")                                          \
                    for (int n = 0; n < 4; ++n)                                \
                        acc[m][h * 4 + n] = __builtin_amdgcn_mfma_f32_16x16x32_bf16( \
                            afr, bfr[n], acc[m][h * 4 + n], 0, 0, 0);          \
                    __builtin_amdgcn_s_setprio(0);                             \
                }                                                              \
            }                                                                  \
        }                                                                      \
    }

__global__ __launch_bounds__(512, 2) void gemm3_kernel(
    const unsigned short* __restrict__ simB,
    const unsigned short* __restrict__ W1T,
    const float* __restrict__ b1, const float* __restrict__ W2,
    float* __restrict__ s_pre) {
    // A: [0,20480) = 320x64, B: [20480,36864) = 256x64, per buffer (72 KB).
    __shared__ unsigned short lds[2][36864];

    const int t    = threadIdx.x;
    const int lane = t & 63;
    const int wv   = t >> 6;
    const int wr   = wv >> 1;          // 0..3  (80-row group)
    const int wc   = wv & 1;           // 0..1  (128-col group)
    const int lr   = lane & 15;
    const int g4   = lane >> 4;        // 0..3
    const int l7   = lane & 7;

    const int bn = blockIdx.x & 7;     // XCD-pinned col slice
    const int bm = blockIdx.x >> 3;    // 0..31
    const int m0 = bm * BM3, n0 = bn * BN3;

    // staging source (pre-swizzled granule so linear LDS dest = swizzled layout)
    const int trow = t >> 3;                       // 0..63
    const int gsrc = (t & 7) ^ (trow & 7);
    const unsigned short* gA = simB + (size_t)(m0 + trow) * KK + gsrc * 8;
    const unsigned short* gB = W1T  + (size_t)(n0 + trow) * KK + gsrc * 8;

    // swizzled ds_read offsets (elements); row&7 == lane&7 for both A and B
    const int aoff = (wr * 80 + lr) * 64;
    const int boff = 20480 + (wc * 128 + lr) * 64;
    const int gx0  = ((0 * 4 + g4) ^ l7) * 8;
    const int gx1  = ((1 * 4 + g4) ^ l7) * 8;

    f32x4 acc[5][8];
#pragma unroll
    for (int m = 0; m < 5; ++m)
#pragma unroll
        for (int n = 0; n < 8; ++n)
            acc[m][n] = (f32x4){0.f, 0.f, 0.f, 0.f};

    // prologue: stage kt=0 into buf 0 (A then B; FIFO order matters)
    STAGE_A(0, 0)
    STAGE_B(0, 0)

#pragma unroll 1
    for (int kt = 0; kt < NKT - 2; kt += 2) {
        BODY(kt,     0, "4", "5", 1)
        BODY(kt + 1, 1, "4", "5", 1)
    }
    BODY(NKT - 2, 0, "4", "5", 1)
    BODY(NKT - 1, 1, "4", "0", 0)

    // epilogue: relu(+b1), dot W2, 16-lane reduce, atomicAdd into s_pre
    float b1v[8], w2v[8];
#pragma unroll
    for (int n = 0; n < 8; ++n) {
        int col = n0 + wc * 128 + n * 16 + lr;
        b1v[n] = b1[col];
        w2v[n] = W2[col];
    }
#pragma unroll
    for (int m = 0; m < 5; ++m) {
#pragma unroll
        for (int r = 0; r < 4; ++r) {
            float rowsum = 0.f;
#pragma unroll
            for (int n = 0; n < 8; ++n) {
                float v = acc[m][n][r] + b1v[n];
                v = fmaxf(v, 0.f);
                rowsum = fmaf(v, w2v[n], rowsum);
            }
            rowsum += __shfl_xor(rowsum, 1);
            rowsum += __shfl_xor(rowsum, 2);
            rowsum += __shfl_xor(rowsum, 4);
            rowsum += __shfl_xor(rowsum, 8);
            if (lr == 0) {
                int row = m0 + wr * 80 + m * 16 + g4 * 4 + r;
                atomicAdd(&s_pre[row], rowsum);
            }
        }
    }
}

// ---------------------------------------------------------------------------
// Fallback GEMM (inline sim staging) — used only if ws too small for simB.
// ---------------------------------------------------------------------------
#define BM 128
#define BN 128
#define BK 32

__global__ __launch_bounds__(256) void gemm_kernel(
    const float* __restrict__ x0, const float* __restrict__ x1,
    const unsigned short* __restrict__ W1T,
    const float* __restrict__ b1, const float* __restrict__ W2,
    float* __restrict__ s_pre) {
    __shared__ unsigned short As[BM][BK];
    __shared__ unsigned short Bs[BN][BK];

    const int tid  = threadIdx.x;
    const int lane = tid & 63;
    const int wave = tid >> 6;
    const int wr = wave >> 1, wc = wave & 1;
    const int bm = blockIdx.x / (DD / BN);
    const int bn = blockIdx.x % (DD / BN);
    const int m0 = bm * BM, n0 = bn * BN;
    const int lr = lane & 15;
    const int lk = (lane >> 4) * 8;

    f32x4 acc[4][4];
#pragma unroll
    for (int m = 0; m < 4; ++m)
#pragma unroll
        for (int n = 0; n < 4; ++n)
            acc[m][n] = (f32x4){0.f, 0.f, 0.f, 0.f};

    for (int k0 = 0; k0 < KK; k0 += BK) {
        __syncthreads();
#pragma unroll
        for (int p = 0; p < 2; ++p) {
            int L  = tid + p * 256;
            int n  = L >> 2;
            int k8 = (L & 3) * 8;
            const unsigned short* g = &W1T[(size_t)(n0 + n) * KK + k0 + k8];
            unsigned short* l = &Bs[0][0] + (size_t)L * 8;
            __builtin_amdgcn_global_load_lds(
                (const __attribute__((address_space(1))) void*)g,
                (__attribute__((address_space(3))) void*)l, 16, 0, 0);
        }
        {
            const int f0 = k0 & (DD - 1);
            const bool second = (k0 >= DD);
            const int fc = (tid & 7) * 4;
            const float4 v0 = *(const float4*)&x0[f0 + fc];
#pragma unroll
            for (int p = 0; p < 4; ++p) {
                int row = p * 32 + (tid >> 3);
                const float4 v1 = *(const float4*)&x1[(size_t)(m0 + row) * DD + f0 + fc];
                ushort4 o;
                o.x = f2bf_rne(second ? (v0.x + v1.x) : fabsf(v0.x - v1.x));
                o.y = f2bf_rne(second ? (v0.y + v1.y) : fabsf(v0.y - v1.y));
                o.z = f2bf_rne(second ? (v0.z + v1.z) : fabsf(v0.z - v1.z));
                o.w = f2bf_rne(second ? (v0.w + v1.w) : fabsf(v0.w - v1.w));
                *(ushort4*)&As[row][fc] = o;
            }
        }
        __syncthreads();

        bf16x8 a[4], b[4];
#pragma unroll
        for (int m = 0; m < 4; ++m)
            a[m] = *(const bf16x8*)&As[wr * 64 + m * 16 + lr][lk];
#pragma unroll
        for (int n = 0; n < 4; ++n)
            b[n] = *(const bf16x8*)&Bs[wc * 64 + n * 16 + lr][lk];
#pragma unroll
        for (int m = 0; m < 4; ++m)
#pragma unroll
            for (int n = 0; n < 4; ++n)
                acc[m][n] = __builtin_amdgcn_mfma_f32_16x16x32_bf16(
                    a[m], b[n], acc[m][n], 0, 0, 0);
    }

    float b1v[4], w2v[4];
#pragma unroll
    for (int n = 0; n < 4; ++n) {
        int col = n0 + wc * 64 + n * 16 + lr;
        b1v[n] = b1[col];
        w2v[n] = W2[col];
    }
#pragma unroll
    for (int m = 0; m < 4; ++m) {
#pragma unroll
        for (int r = 0; r < 4; ++r) {
            float rowsum = 0.f;
#pragma unroll
            for (int n = 0; n < 4; ++n) {
                float v = acc[m][n][r] + b1v[n];
                v = fmaxf(v, 0.f);
                rowsum = fmaf(v, w2v[n], rowsum);
            }
            rowsum += __shfl_xor(rowsum, 1);
            rowsum += __shfl_xor(rowsum, 2);
            rowsum += __shfl_xor(rowsum, 4);
            rowsum += __shfl_xor(rowsum, 8);
            if (lr == 0) {
                int row = m0 + wr * 64 + m * 16 + (lane >> 4) * 4 + r;
                atomicAdd(&s_pre[row], rowsum);
            }
        }
    }
}

// ---------------------------------------------------------------------------
// Chunk-parallel BiLSTM. CHUNK=64, WARM=192 (worst-case contraction 0.95 ->
// boundary error ~5e-5 << 1e-2; typical ~1e-16). 320 chunk-threads.
// ---------------------------------------------------------------------------
#define CHUNK 64
#define WARM  192
#define NCH   (SS / CHUNK)   // 160

__device__ __forceinline__ float sigf(float x) {
    return 1.f / (1.f + __expf(-x));
}
__device__ __forceinline__ float tanhfast(float x) {
    return 2.f / (1.f + __expf(-2.f * x)) - 1.f;
}

__global__ __launch_bounds__(64) void lstm_kernel(
    const float* __restrict__ s_pre,
    const float* __restrict__ Wih_f, const float* __restrict__ Whh_f,
    const float* __restrict__ bih_f, const float* __restrict__ bhh_f,
    const float* __restrict__ Wih_b, const float* __restrict__ Whh_b,
    const float* __restrict__ bih_b, const float* __restrict__ bhh_b,
    float* __restrict__ hf, float* __restrict__ hb) {
    int id = blockIdx.x * blockDim.x + threadIdx.x;
    if (id >= 2 * NCH) return;
    int dir = id / NCH;
    int ch  = id % NCH;
    const float* Wih = dir ? Wih_b : Wih_f;
    const float* Whh = dir ? Whh_b : Whh_f;
    const float* bih = dir ? bih_b : bih_f;
    const float* bhh = dir ? bhh_b : bhh_f;
    const float wi0 = Wih[0], wi1 = Wih[1], wi2 = Wih[2], wi3 = Wih[3];
    const float wh0 = Whh[0], wh1 = Whh[1], wh2 = Whh[2], wh3 = Whh[3];
    const float bb0 = bih[0] + bhh[0], bb1 = bih[1] + bhh[1];
    const float bb2 = bih[2] + bhh[2], bb3 = bih[3] + bhh[3];

    const int pout0 = ch * CHUNK;
    int pstart = pout0 - WARM; if (pstart < 0) pstart = 0;
    const int pend = pout0 + CHUNK;

    float h = 0.f, c = 0.f;
    for (int p = pstart; p < pend; ++p) {
        int s = dir ? (SS - 1 - p) : p;
        float x  = sigf(s_pre[s]);
        float g0 = fmaf(wi0, x, fmaf(wh0, h, bb0));
        float g1 = fmaf(wi1, x, fmaf(wh1, h, bb1));
        float g2 = fmaf(wi2, x, fmaf(wh2, h, bb2));
        float g3 = fmaf(wi3, x, fmaf(wh3, h, bb3));
        float gi = sigf(g0);
        float gf = sigf(g1);
        float gg = tanhfast(g2);
        float go = sigf(g3);
        c = fmaf(gf, c, gi * gg);
        h = go * tanhfast(c);
        if (p >= pout0) {
            if (dir) hb[s] = h; else hf[s] = h;
        }
    }
}

// ---------------------------------------------------------------------------
// Head
// ---------------------------------------------------------------------------
__global__ __launch_bounds__(256) void final_kernel(
    const float* __restrict__ hf, const float* __restrict__ hb,
    const float* __restrict__ W3, const float* __restrict__ b3,
    float* __restrict__ out) {
    int j = blockIdx.x * blockDim.x + threadIdx.x;
    if (j >= (SS * 2) / 10) return;   // 2048
    float acc = b3[0];
#pragma unroll
    for (int i = 0; i < 5; ++i) {
        acc = fmaf(hf[5 * j + i], W3[2 * i],     acc);
        acc = fmaf(hb[5 * j + i], W3[2 * i + 1], acc);
    }
    out[j] = sigf(acc);
}

// ---------------------------------------------------------------------------
extern "C" void kernel_launch(void* const* d_in, const int* in_sizes, int n_in,
                              void* d_out, int out_size, void* d_ws, size_t ws_size,
                              hipStream_t stream) {
    const float* x0    = (const float*)d_in[0];
    const float* x1    = (const float*)d_in[1];
    const float* W1    = (const float*)d_in[2];
    const float* b1    = (const float*)d_in[3];
    const float* W2    = (const float*)d_in[4];
    const float* b2    = (const float*)d_in[5];
    const float* Wih_f = (const float*)d_in[6];
    const float* Whh_f = (const float*)d_in[7];
    const float* bih_f = (const float*)d_in[8];
    const float* bhh_f = (const float*)d_in[9];
    const float* Wih_b = (const float*)d_in[10];
    const float* Whh_b = (const float*)d_in[11];
    const float* bih_b = (const float*)d_in[12];
    const float* bhh_b = (const float*)d_in[13];
    const float* W3    = (const float*)d_in[14];
    const float* b3    = (const float*)d_in[15];
    float* out = (float*)d_out;

    char* ws = (char*)d_ws;
    const size_t w1t_bytes = (size_t)KK * DD * 2;        // 16 MB
    unsigned short* W1T = (unsigned short*)ws;
    float* s_pre = (float*)(ws + w1t_bytes);             // 40 KB
    float* hf    = s_pre + SS;
    float* hb    = hf + SS;
    size_t off_sim = w1t_bytes + 3 * (size_t)SS * 4;
    off_sim = (off_sim + 255) & ~(size_t)255;
    unsigned short* simB = (unsigned short*)(ws + off_sim);
    const size_t need = off_sim + (size_t)SS * KK * 2;   // ~100.8 MB

    prep_kernel<<<(KK / 64) * (DD / 64), 256, 0, stream>>>(W1, b2, W1T, s_pre);
    if (ws_size >= need) {
        sim_kernel<<<SS, 256, 0, stream>>>(x0, x1, simB);
        gemm3_kernel<<<(SS / BM3) * (DD / BN3), 512, 0, stream>>>(
            simB, W1T, b1, W2, s_pre);
    } else {
        gemm_kernel<<<(SS / BM) * (DD / BN), 256, 0, stream>>>(
            x0, x1, W1T, b1, W2, s_pre);
    }
    lstm_kernel<<<(2 * NCH + 63) / 64, 64, 0, stream>>>(
        s_pre, Wih_f, Whh_f, bih_f, bhh_f, Wih_b, Whh_b, bih_b, bhh_b, hf, hb);
    final_kernel<<<((SS * 2) / 10 + 255) / 256, 256, 0, stream>>>(hf, hb, W3, b3, out);
}

// Round 5
// 400.334 us; speedup vs baseline: 1.5743x; 1.0389x over previous
//
#include <hip/hip_runtime.h>
#include <hip/hip_bf16.h>

// Problem constants
#define DD 2048
#define SS 10240
#define KK 4096   // 2*DD

typedef __bf16 bf16x8 __attribute__((ext_vector_type(8)));
typedef float  f32x4  __attribute__((ext_vector_type(4)));

__device__ __forceinline__ unsigned short f2bf_rne(float x) {
    unsigned int u = __float_as_uint(x);
    u += 0x7FFFu + ((u >> 16) & 1u);
    return (unsigned short)(u >> 16);
}

// ---------------------------------------------------------------------------
// Fused prep+sim (one launch):
//  blocks [0,2048):      W1 [4096][2048] f32 -> W1T [2048][4096] bf16,
//                        plus s_pre init = b2
//  blocks [2048,12288):  sim row s = blockIdx-2048: bf16 [SS][KK]
// ---------------------------------------------------------------------------
__global__ __launch_bounds__(256) void prep_sim_kernel(
    const float* __restrict__ W1, const float* __restrict__ b2,
    const float* __restrict__ x0, const float* __restrict__ x1,
    unsigned short* __restrict__ W1T, float* __restrict__ s_pre,
    unsigned short* __restrict__ simB) {
    __shared__ float tile[64][65];
    const int t = threadIdx.x;

    if (blockIdx.x < (KK / 64) * (DD / 64)) {
        // ---- transpose W1 -> W1T (bf16) ----
        const int bf = blockIdx.x % (KK / 64);
        const int bd = blockIdx.x / (KK / 64);
        const int f0 = bf * 64, d0 = bd * 64;
#pragma unroll
        for (int p = 0; p < 4; ++p) {
            int fr = p * 16 + (t >> 4);
            int dc = (t & 15) * 4;
            const float4 v = *(const float4*)&W1[(size_t)(f0 + fr) * DD + d0 + dc];
            tile[fr][dc + 0] = v.x; tile[fr][dc + 1] = v.y;
            tile[fr][dc + 2] = v.z; tile[fr][dc + 3] = v.w;
        }
        __syncthreads();
#pragma unroll
        for (int p = 0; p < 4; ++p) {
            int dr = p * 16 + (t >> 4);
            int fc = (t & 15) * 4;
            ushort4 o;
            o.x = f2bf_rne(tile[fc + 0][dr]);
            o.y = f2bf_rne(tile[fc + 1][dr]);
            o.z = f2bf_rne(tile[fc + 2][dr]);
            o.w = f2bf_rne(tile[fc + 3][dr]);
            *(ushort4*)&W1T[(size_t)(d0 + dr) * KK + f0 + fc] = o;
        }
        int gid = blockIdx.x * 256 + t;
        if (gid < SS) s_pre[gid] = b2[0];
    } else {
        // ---- sim row ----
        const int s = blockIdx.x - (KK / 64) * (DD / 64);
        const int d = t * 8;
        const float4 a0 = *(const float4*)&x0[d];
        const float4 a1 = *(const float4*)&x0[d + 4];
        const float4 v0 = *(const float4*)&x1[(size_t)s * DD + d];
        const float4 v1 = *(const float4*)&x1[(size_t)s * DD + d + 4];
        ushort4 lo0, lo1, hi0, hi1;
        lo0.x = f2bf_rne(fabsf(a0.x - v0.x)); hi0.x = f2bf_rne(a0.x + v0.x);
        lo0.y = f2bf_rne(fabsf(a0.y - v0.y)); hi0.y = f2bf_rne(a0.y + v0.y);
        lo0.z = f2bf_rne(fabsf(a0.z - v0.z)); hi0.z = f2bf_rne(a0.z + v0.z);
        lo0.w = f2bf_rne(fabsf(a0.w - v0.w)); hi0.w = f2bf_rne(a0.w + v0.w);
        lo1.x = f2bf_rne(fabsf(a1.x - v1.x)); hi1.x = f2bf_rne(a1.x + v1.x);
        lo1.y = f2bf_rne(fabsf(a1.y - v1.y)); hi1.y = f2bf_rne(a1.y + v1.y);
        lo1.z = f2bf_rne(fabsf(a1.z - v1.z)); hi1.z = f2bf_rne(a1.z + v1.z);
        lo1.w = f2bf_rne(fabsf(a1.w - v1.w)); hi1.w = f2bf_rne(a1.w + v1.w);
        unsigned short* row = &simB[(size_t)s * KK];
        *(ushort4*)&row[d]          = lo0;
        *(ushort4*)&row[d + 4]      = lo1;
        *(ushort4*)&row[DD + d]     = hi0;
        *(ushort4*)&row[DD + d + 4] = hi1;
    }
}

// ---------------------------------------------------------------------------
// gemm3: 320x256 tile, BK=64, 512 thr (8 waves 4x2, wave out 80x128).
// Counted-vmcnt double-buffer pipeline (no __syncthreads, no vmcnt(0) in
// steady loop). T2 XOR swizzle via pre-swizzled global source (rule #21).
// grid 256 blocks = 1/CU. XCD pinning: bm = i&31 (A-panel per XCD; panel
// 2.56 MB < 4 MB L2; B shared via L3).
// ---------------------------------------------------------------------------
#define BM3 320
#define BN3 256
#define BK3 64
#define NKT (KK / BK3)   // 64

// stage A: 5 rounds x 512 thr x 16B = 40 KB (320 rows x 128 B)
#define STAGE_A(ktv, BUFV)                                                     \
    _Pragma("unroll")                                                          \
    for (int L = 0; L < 5; ++L) {                                              \
        __builtin_amdgcn_global_load_lds(                                      \
            (const __attribute__((address_space(1))) void*)(gA + (size_t)L * 64 * KK + (size_t)(ktv) * 64), \
            (__attribute__((address_space(3))) void*)&lds[BUFV][t * 8 + L * 4096], \
            16, 0, 0);                                                         \
    }
// stage B: 4 rounds = 32 KB (256 rows x 128 B)
#define STAGE_B(ktv, BUFV)                                                     \
    _Pragma("unroll")                                                          \
    for (int L = 0; L < 4; ++L) {                                              \
        __builtin_amdgcn_global_load_lds(                                      \
            (const __attribute__((address_space(1))) void*)(gB + (size_t)L * 64 * KK + (size_t)(ktv) * 64), \
            (__attribute__((address_space(3))) void*)&lds[BUFV][20480 + t * 8 + L * 4096], \
            16, 0, 0);                                                         \
    }

// Minimal LDS-read inner loop: 16 B-frag + 10 A-frag ds_read_b128 per BODY
// (VGPR headroom proven in R4: acc lives in AGPRs, VGPR_Count was 124).
#define BODY(ktv, BUF, SA_LIT, SB_LIT, DO_STAGE)                               \
    {                                                                          \
        asm volatile("s_waitcnt vmcnt(" SA_LIT ")" ::: "memory");              \
        __builtin_amdgcn_s_barrier();                                          \
        __builtin_amdgcn_sched_barrier(0);                                     \
        if (DO_STAGE) { STAGE_A((ktv) + 1, BUF ^ 1) }                          \
        asm volatile("s_waitcnt vmcnt(" SB_LIT ")" ::: "memory");              \
        __builtin_amdgcn_s_barrier();                                          \
        __builtin_amdgcn_sched_barrier(0);                                     \
        if (DO_STAGE) { STAGE_B((ktv) + 1, BUF ^ 1) }                          \
        _Pragma("unroll")                                                      \
        for (int ks = 0; ks < 2; ++ks) {                                       \
            const int gx = ks ? gx1 : gx0;                                     \
            bf16x8 bfr[8];                                                     \
            _Pragma("unroll")                                                  \
            for (int n = 0; n < 8; ++n)                                        \
                bfr[n] = *(const bf16x8*)&lds[BUF][boff + n * 1024 + gx];      \
            _Pragma("unroll")                                                  \
            for (int m = 0; m < 5; ++m) {                                      \
                bf16x8 afr = *(const bf16x8*)&lds[BUF][aoff + m * 1024 + gx];  \
                __builtin_amdgcn_s_setprio(1);                                 \
                _Pragma("unroll")                                              \
                for (int n = 0; n < 8; ++n)                                    \
                    acc[m][n] = __builtin_amdgcn_mfma_f32_16x16x32_bf16(       \
                        afr, bfr[n], acc[m][n], 0, 0, 0);                      \
                __builtin_amdgcn_s_setprio(0);                                 \
            }                                                                  \
        }                                                                      \
    }

__global__ __launch_bounds__(512, 2) void gemm3_kernel(
    const unsigned short* __restrict__ simB,
    const unsigned short* __restrict__ W1T,
    const float* __restrict__ b1, const float* __restrict__ W2,
    float* __restrict__ s_pre) {
    // A: [0,20480) = 320x64, B: [20480,36864) = 256x64, per buffer (72 KB).
    __shared__ unsigned short lds[2][36864];

    const int t    = threadIdx.x;
    const int lane = t & 63;
    const int wv   = t >> 6;
    const int wr   = wv >> 1;          // 0..3  (80-row group)
    const int wc   = wv & 1;           // 0..1  (128-col group)
    const int lr   = lane & 15;
    const int g4   = lane >> 4;        // 0..3
    const int l7   = lane & 7;

    // A-panel-per-XCD pinning: same-bm blocks are i === bm (mod 32) -> same XCD.
    const int bm = blockIdx.x & 31;
    const int bn = blockIdx.x >> 5;    // 0..7
    const int m0 = bm * BM3, n0 = bn * BN3;

    // staging source (pre-swizzled granule so linear LDS dest = swizzled layout)
    const int trow = t >> 3;                       // 0..63
    const int gsrc = (t & 7) ^ (trow & 7);
    const unsigned short* gA = simB + (size_t)(m0 + trow) * KK + gsrc * 8;
    const unsigned short* gB = W1T  + (size_t)(n0 + trow) * KK + gsrc * 8;

    // swizzled ds_read offsets (elements); row&7 == lane&7 for both A and B
    const int aoff = (wr * 80 + lr) * 64;
    const int boff = 20480 + (wc * 128 + lr) * 64;
    const int gx0  = ((0 * 4 + g4) ^ l7) * 8;
    const int gx1  = ((1 * 4 + g4) ^ l7) * 8;

    f32x4 acc[5][8];
#pragma unroll
    for (int m = 0; m < 5; ++m)
#pragma unroll
        for (int n = 0; n < 8; ++n)
            acc[m][n] = (f32x4){0.f, 0.f, 0.f, 0.f};

    // prologue: stage kt=0 into buf 0 (A then B; FIFO order matters)
    STAGE_A(0, 0)
    STAGE_B(0, 0)

#pragma unroll 1
    for (int kt = 0; kt < NKT - 2; kt += 2) {
        BODY(kt,     0, "4", "5", 1)
        BODY(kt + 1, 1, "4", "5", 1)
    }
    BODY(NKT - 2, 0, "4", "5", 1)
    BODY(NKT - 1, 1, "4", "0", 0)

    // epilogue: relu(+b1), dot W2, 16-lane reduce, atomicAdd into s_pre
    float b1v[8], w2v[8];
#pragma unroll
    for (int n = 0; n < 8; ++n) {
        int col = n0 + wc * 128 + n * 16 + lr;
        b1v[n] = b1[col];
        w2v[n] = W2[col];
    }
#pragma unroll
    for (int m = 0; m < 5; ++m) {
#pragma unroll
        for (int r = 0; r < 4; ++r) {
            float rowsum = 0.f;
#pragma unroll
            for (int n = 0; n < 8; ++n) {
                float v = acc[m][n][r] + b1v[n];
                v = fmaxf(v, 0.f);
                rowsum = fmaf(v, w2v[n], rowsum);
            }
            rowsum += __shfl_xor(rowsum, 1);
            rowsum += __shfl_xor(rowsum, 2);
            rowsum += __shfl_xor(rowsum, 4);
            rowsum += __shfl_xor(rowsum, 8);
            if (lr == 0) {
                int row = m0 + wr * 80 + m * 16 + g4 * 4 + r;
                atomicAdd(&s_pre[row], rowsum);
            }
        }
    }
}

// ---------------------------------------------------------------------------
// Fallback GEMM (inline sim staging) — used only if ws too small for simB.
// ---------------------------------------------------------------------------
#define BM 128
#define BN 128
#define BK 32

__global__ __launch_bounds__(256) void gemm_kernel(
    const float* __restrict__ x0, const float* __restrict__ x1,
    const unsigned short* __restrict__ W1T,
    const float* __restrict__ b1, const float* __restrict__ W2,
    float* __restrict__ s_pre) {
    __shared__ unsigned short As[BM][BK];
    __shared__ unsigned short Bs[BN][BK];

    const int tid  = threadIdx.x;
    const int lane = tid & 63;
    const int wave = tid >> 6;
    const int wr = wave >> 1, wc = wave & 1;
    const int bm = blockIdx.x / (DD / BN);
    const int bn = blockIdx.x % (DD / BN);
    const int m0 = bm * BM, n0 = bn * BN;
    const int lr = lane & 15;
    const int lk = (lane >> 4) * 8;

    f32x4 acc[4][4];
#pragma unroll
    for (int m = 0; m < 4; ++m)
#pragma unroll
        for (int n = 0; n < 4; ++n)
            acc[m][n] = (f32x4){0.f, 0.f, 0.f, 0.f};

    for (int k0 = 0; k0 < KK; k0 += BK) {
        __syncthreads();
#pragma unroll
        for (int p = 0; p < 2; ++p) {
            int L  = tid + p * 256;
            int n  = L >> 2;
            int k8 = (L & 3) * 8;
            const unsigned short* g = &W1T[(size_t)(n0 + n) * KK + k0 + k8];
            unsigned short* l = &Bs[0][0] + (size_t)L * 8;
            __builtin_amdgcn_global_load_lds(
                (const __attribute__((address_space(1))) void*)g,
                (__attribute__((address_space(3))) void*)l, 16, 0, 0);
        }
        {
            const int f0 = k0 & (DD - 1);
            const bool second = (k0 >= DD);
            const int fc = (tid & 7) * 4;
            const float4 v0 = *(const float4*)&x0[f0 + fc];
#pragma unroll
            for (int p = 0; p < 4; ++p) {
                int row = p * 32 + (tid >> 3);
                const float4 v1 = *(const float4*)&x1[(size_t)(m0 + row) * DD + f0 + fc];
                ushort4 o;
                o.x = f2bf_rne(second ? (v0.x + v1.x) : fabsf(v0.x - v1.x));
                o.y = f2bf_rne(second ? (v0.y + v1.y) : fabsf(v0.y - v1.y));
                o.z = f2bf_rne(second ? (v0.z + v1.z) : fabsf(v0.z - v1.z));
                o.w = f2bf_rne(second ? (v0.w + v1.w) : fabsf(v0.w - v1.w));
                *(ushort4*)&As[row][fc] = o;
            }
        }
        __syncthreads();

        bf16x8 a[4], b[4];
#pragma unroll
        for (int m = 0; m < 4; ++m)
            a[m] = *(const bf16x8*)&As[wr * 64 + m * 16 + lr][lk];
#pragma unroll
        for (int n = 0; n < 4; ++n)
            b[n] = *(const bf16x8*)&Bs[wc * 64 + n * 16 + lr][lk];
#pragma unroll
        for (int m = 0; m < 4; ++m)
#pragma unroll
            for (int n = 0; n < 4; ++n)
                acc[m][n] = __builtin_amdgcn_mfma_f32_16x16x32_bf16(
                    a[m], b[n], acc[m][n], 0, 0, 0);
    }

    float b1v[4], w2v[4];
#pragma unroll
    for (int n = 0; n < 4; ++n) {
        int col = n0 + wc * 64 + n * 16 + lr;
        b1v[n] = b1[col];
        w2v[n] = W2[col];
    }
#pragma unroll
    for (int m = 0; m < 4; ++m) {
#pragma unroll
        for (int r = 0; r < 4; ++r) {
            float rowsum = 0.f;
#pragma unroll
            for (int n = 0; n < 4; ++n) {
                float v = acc[m][n][r] + b1v[n];
                v = fmaxf(v, 0.f);
                rowsum = fmaf(v, w2v[n], rowsum);
            }
            rowsum += __shfl_xor(rowsum, 1);
            rowsum += __shfl_xor(rowsum, 2);
            rowsum += __shfl_xor(rowsum, 4);
            rowsum += __shfl_xor(rowsum, 8);
            if (lr == 0) {
                int row = m0 + wr * 64 + m * 16 + (lane >> 4) * 4 + r;
                atomicAdd(&s_pre[row], rowsum);
            }
        }
    }
}

// ---------------------------------------------------------------------------
// Chunk-parallel BiLSTM. CHUNK=64, WARM=192 (worst-case contraction 0.95 ->
// boundary error ~5e-5 << 1e-2; typical ~1e-16). Verified R4 (absmax 0).
// ---------------------------------------------------------------------------
#define CHUNK 64
#define WARM  192
#define NCH   (SS / CHUNK)   // 160

__device__ __forceinline__ float sigf(float x) {
    return 1.f / (1.f + __expf(-x));
}
__device__ __forceinline__ float tanhfast(float x) {
    return 2.f / (1.f + __expf(-2.f * x)) - 1.f;
}

__global__ __launch_bounds__(64) void lstm_kernel(
    const float* __restrict__ s_pre,
    const float* __restrict__ Wih_f, const float* __restrict__ Whh_f,
    const float* __restrict__ bih_f, const float* __restrict__ bhh_f,
    const float* __restrict__ Wih_b, const float* __restrict__ Whh_b,
    const float* __restrict__ bih_b, const float* __restrict__ bhh_b,
    float* __restrict__ hf, float* __restrict__ hb) {
    int id = blockIdx.x * blockDim.x + threadIdx.x;
    if (id >= 2 * NCH) return;
    int dir = id / NCH;
    int ch  = id % NCH;
    const float* Wih = dir ? Wih_b : Wih_f;
    const float* Whh = dir ? Whh_b : Whh_f;
    const float* bih = dir ? bih_b : bih_f;
    const float* bhh = dir ? bhh_b : bhh_f;
    const float wi0 = Wih[0], wi1 = Wih[1], wi2 = Wih[2], wi3 = Wih[3];
    const float wh0 = Whh[0], wh1 = Whh[1], wh2 = Whh[2], wh3 = Whh[3];
    const float bb0 = bih[0] + bhh[0], bb1 = bih[1] + bhh[1];
    const float bb2 = bih[2] + bhh[2], bb3 = bih[3] + bhh[3];

    const int pout0 = ch * CHUNK;
    int pstart = pout0 - WARM; if (pstart < 0) pstart = 0;
    const int pend = pout0 + CHUNK;

    float h = 0.f, c = 0.f;
    for (int p = pstart; p < pend; ++p) {
        int s = dir ? (SS - 1 - p) : p;
        float x  = sigf(s_pre[s]);
        float g0 = fmaf(wi0, x, fmaf(wh0, h, bb0));
        float g1 = fmaf(wi1, x, fmaf(wh1, h, bb1));
        float g2 = fmaf(wi2, x, fmaf(wh2, h, bb2));
        float g3 = fmaf(wi3, x, fmaf(wh3, h, bb3));
        float gi = sigf(g0);
        float gf = sigf(g1);
        float gg = tanhfast(g2);
        float go = sigf(g3);
        c = fmaf(gf, c, gi * gg);
        h = go * tanhfast(c);
        if (p >= pout0) {
            if (dir) hb[s] = h; else hf[s] = h;
        }
    }
}

// ---------------------------------------------------------------------------
// Head
// ---------------------------------------------------------------------------
__global__ __launch_bounds__(256) void final_kernel(
    const float* __restrict__ hf, const float* __restrict__ hb,
    const float* __restrict__ W3, const float* __restrict__ b3,
    float* __restrict__ out) {
    int j = blockIdx.x * blockDim.x + threadIdx.x;
    if (j >= (SS * 2) / 10) return;   // 2048
    float acc = b3[0];
#pragma unroll
    for (int i = 0; i < 5; ++i) {
        acc = fmaf(hf[5 * j + i], W3[2 * i],     acc);
        acc = fmaf(hb[5 * j + i], W3[2 * i + 1], acc);
    }
    out[j] = sigf(acc);
}

// ---------------------------------------------------------------------------
extern "C" void kernel_launch(void* const* d_in, const int* in_sizes, int n_in,
                              void* d_out, int out_size, void* d_ws, size_t ws_size,
                              hipStream_t stream) {
    const float* x0    = (const float*)d_in[0];
    const float* x1    = (const float*)d_in[1];
    const float* W1    = (const float*)d_in[2];
    const float* b1    = (const float*)d_in[3];
    const float* W2    = (const float*)d_in[4];
    const float* b2    = (const float*)d_in[5];
    const float* Wih_f = (const float*)d_in[6];
    const float* Whh_f = (const float*)d_in[7];
    const float* bih_f = (const float*)d_in[8];
    const float* bhh_f = (const float*)d_in[9];
    const float* Wih_b = (const float*)d_in[10];
    const float* Whh_b = (const float*)d_in[11];
    const float* bih_b = (const float*)d_in[12];
    const float* bhh_b = (const float*)d_in[13];
    const float* W3    = (const float*)d_in[14];
    const float* b3    = (const float*)d_in[15];
    float* out = (float*)d_out;

    char* ws = (char*)d_ws;
    const size_t w1t_bytes = (size_t)KK * DD * 2;        // 16 MB
    unsigned short* W1T = (unsigned short*)ws;
    float* s_pre = (float*)(ws + w1t_bytes);             // 40 KB
    float* hf    = s_pre + SS;
    float* hb    = hf + SS;
    size_t off_sim = w1t_bytes + 3 * (size_t)SS * 4;
    off_sim = (off_sim + 255) & ~(size_t)255;
    unsigned short* simB = (unsigned short*)(ws + off_sim);
    const size_t need = off_sim + (size_t)SS * KK * 2;   // ~100.8 MB

    if (ws_size >= need) {
        prep_sim_kernel<<<(KK / 64) * (DD / 64) + SS, 256, 0, stream>>>(
            W1, b2, x0, x1, W1T, s_pre, simB);
        gemm3_kernel<<<(SS / BM3) * (DD / BN3), 512, 0, stream>>>(
            simB, W1T, b1, W2, s_pre);
    } else {
        prep_sim_kernel<<<(KK / 64) * (DD / 64), 256, 0, stream>>>(
            W1, b2, x0, x1, W1T, s_pre, simB);
        gemm_kernel<<<(SS / BM) * (DD / BN), 256, 0, stream>>>(
            x0, x1, W1T, b1, W2, s_pre);
    }
    lstm_kernel<<<(2 * NCH + 63) / 64, 64, 0, stream>>>(
        s_pre, Wih_f, Whh_f, bih_f, bhh_f, Wih_b, Whh_b, bih_b, bhh_b, hf, hb);
    final_kernel<<<((SS * 2) / 10 + 255) / 256, 256, 0, stream>>>(hf, hb, W3, b3, out);
}

// Round 6
// 388.363 us; speedup vs baseline: 1.6228x; 1.0308x over previous
//
#include <hip/hip_runtime.h>
#include <hip/hip_bf16.h>

// Problem constants
#define DD 2048
#define SS 10240
#define KK 4096   // 2*DD

typedef __bf16 bf16x8 __attribute__((ext_vector_type(8)));
typedef float  f32x4  __attribute__((ext_vector_type(4)));

__device__ __forceinline__ unsigned short f2bf_rne(float x) {
    unsigned int u = __float_as_uint(x);
    u += 0x7FFFu + ((u >> 16) & 1u);
    return (unsigned short)(u >> 16);
}

// ---------------------------------------------------------------------------
// Fused prep+sim (one launch):
//  blocks [0,2048):      W1 [4096][2048] f32 -> W1T [2048][4096] bf16,
//                        plus s_pre init = b2
//  blocks [2048,12288):  sim row s = blockIdx-2048: bf16 [SS][KK]
// ---------------------------------------------------------------------------
__global__ __launch_bounds__(256) void prep_sim_kernel(
    const float* __restrict__ W1, const float* __restrict__ b2,
    const float* __restrict__ x0, const float* __restrict__ x1,
    unsigned short* __restrict__ W1T, float* __restrict__ s_pre,
    unsigned short* __restrict__ simB) {
    __shared__ float tile[64][65];
    const int t = threadIdx.x;

    if (blockIdx.x < (KK / 64) * (DD / 64)) {
        // ---- transpose W1 -> W1T (bf16) ----
        const int bf = blockIdx.x % (KK / 64);
        const int bd = blockIdx.x / (KK / 64);
        const int f0 = bf * 64, d0 = bd * 64;
#pragma unroll
        for (int p = 0; p < 4; ++p) {
            int fr = p * 16 + (t >> 4);
            int dc = (t & 15) * 4;
            const float4 v = *(const float4*)&W1[(size_t)(f0 + fr) * DD + d0 + dc];
            tile[fr][dc + 0] = v.x; tile[fr][dc + 1] = v.y;
            tile[fr][dc + 2] = v.z; tile[fr][dc + 3] = v.w;
        }
        __syncthreads();
#pragma unroll
        for (int p = 0; p < 4; ++p) {
            int dr = p * 16 + (t >> 4);
            int fc = (t & 15) * 4;
            ushort4 o;
            o.x = f2bf_rne(tile[fc + 0][dr]);
            o.y = f2bf_rne(tile[fc + 1][dr]);
            o.z = f2bf_rne(tile[fc + 2][dr]);
            o.w = f2bf_rne(tile[fc + 3][dr]);
            *(ushort4*)&W1T[(size_t)(d0 + dr) * KK + f0 + fc] = o;
        }
        int gid = blockIdx.x * 256 + t;
        if (gid < SS) s_pre[gid] = b2[0];
    } else {
        // ---- sim row ----
        const int s = blockIdx.x - (KK / 64) * (DD / 64);
        const int d = t * 8;
        const float4 a0 = *(const float4*)&x0[d];
        const float4 a1 = *(const float4*)&x0[d + 4];
        const float4 v0 = *(const float4*)&x1[(size_t)s * DD + d];
        const float4 v1 = *(const float4*)&x1[(size_t)s * DD + d + 4];
        ushort4 lo0, lo1, hi0, hi1;
        lo0.x = f2bf_rne(fabsf(a0.x - v0.x)); hi0.x = f2bf_rne(a0.x + v0.x);
        lo0.y = f2bf_rne(fabsf(a0.y - v0.y)); hi0.y = f2bf_rne(a0.y + v0.y);
        lo0.z = f2bf_rne(fabsf(a0.z - v0.z)); hi0.z = f2bf_rne(a0.z + v0.z);
        lo0.w = f2bf_rne(fabsf(a0.w - v0.w)); hi0.w = f2bf_rne(a0.w + v0.w);
        lo1.x = f2bf_rne(fabsf(a1.x - v1.x)); hi1.x = f2bf_rne(a1.x + v1.x);
        lo1.y = f2bf_rne(fabsf(a1.y - v1.y)); hi1.y = f2bf_rne(a1.y + v1.y);
        lo1.z = f2bf_rne(fabsf(a1.z - v1.z)); hi1.z = f2bf_rne(a1.z + v1.z);
        lo1.w = f2bf_rne(fabsf(a1.w - v1.w)); hi1.w = f2bf_rne(a1.w + v1.w);
        unsigned short* row = &simB[(size_t)s * KK];
        *(ushort4*)&row[d]          = lo0;
        *(ushort4*)&row[d + 4]      = lo1;
        *(ushort4*)&row[DD + d]     = hi0;
        *(ushort4*)&row[DD + d + 4] = hi1;
    }
}

// ---------------------------------------------------------------------------
// gemm3: 320x256 tile, BK=64, 512 thr (8 waves 4x2, wave out 80x128).
// Counted-vmcnt double-buffer pipeline + 4-phase MFMA rhythm (m201-style):
// each phase = {ds_read cluster; s_barrier; setprio(1); 20 MFMA; setprio(0)}.
// Phase barriers are scheduling-only (phases read disjoint LDS; staging
// writes target the other buffer) - counted vmcnt semantics unchanged.
// T2 XOR swizzle via pre-swizzled global source (rule #21). grid 256 = 1/CU.
// XCD pinning: bm = i&31 (A-panel per XCD, 2.56 MB < 4 MB L2).
// ---------------------------------------------------------------------------
#define BM3 320
#define BN3 256
#define BK3 64
#define NKT (KK / BK3)   // 64

// stage A: 5 rounds x 512 thr x 16B = 40 KB (320 rows x 128 B)
#define STAGE_A(ktv, BUFV)                                                     \
    _Pragma("unroll")                                                          \
    for (int L = 0; L < 5; ++L) {                                              \
        __builtin_amdgcn_global_load_lds(                                      \
            (const __attribute__((address_space(1))) void*)(gA + (size_t)L * 64 * KK + (size_t)(ktv) * 64), \
            (__attribute__((address_space(3))) void*)&lds[BUFV][t * 8 + L * 4096], \
            16, 0, 0);                                                         \
    }
// stage B: 4 rounds = 32 KB (256 rows x 128 B)
#define STAGE_B(ktv, BUFV)                                                     \
    _Pragma("unroll")                                                          \
    for (int L = 0; L < 4; ++L) {                                              \
        __builtin_amdgcn_global_load_lds(                                      \
            (const __attribute__((address_space(1))) void*)(gB + (size_t)L * 64 * KK + (size_t)(ktv) * 64), \
            (__attribute__((address_space(3))) void*)&lds[BUFV][20480 + t * 8 + L * 4096], \
            16, 0, 0);                                                         \
    }

#define BODY(ktv, BUF, SA_LIT, SB_LIT, DO_STAGE)                               \
    {                                                                          \
        asm volatile("s_waitcnt vmcnt(" SA_LIT ")" ::: "memory");              \
        __builtin_amdgcn_s_barrier();                                          \
        __builtin_amdgcn_sched_barrier(0);                                     \
        if (DO_STAGE) { STAGE_A((ktv) + 1, BUF ^ 1) }                          \
        asm volatile("s_waitcnt vmcnt(" SB_LIT ")" ::: "memory");              \
        __builtin_amdgcn_s_barrier();                                          \
        __builtin_amdgcn_sched_barrier(0);                                     \
        if (DO_STAGE) { STAGE_B((ktv) + 1, BUF ^ 1) }                          \
        _Pragma("unroll")                                                      \
        for (int ks = 0; ks < 2; ++ks) {                                       \
            const int gx = ks ? gx1 : gx0;                                     \
            bf16x8 afr[5], bfr[4];                                             \
            _Pragma("unroll")                                                  \
            for (int m = 0; m < 5; ++m)                                        \
                afr[m] = *(const bf16x8*)&lds[BUF][aoff + m * 1024 + gx];      \
            _Pragma("unroll")                                                  \
            for (int n = 0; n < 4; ++n)                                        \
                bfr[n] = *(const bf16x8*)&lds[BUF][boff + n * 1024 + gx];      \
            __builtin_amdgcn_s_barrier();                                      \
            __builtin_amdgcn_s_setprio(1);                                     \
            _Pragma("unroll")                                                  \
            for (int m = 0; m < 5; ++m)                                        \
                _Pragma("unroll")                                              \
                for (int n = 0; n < 4; ++n)                                    \
                    acc[m][n] = __builtin_amdgcn_mfma_f32_16x16x32_bf16(       \
                        afr[m], bfr[n], acc[m][n], 0, 0, 0);                   \
            __builtin_amdgcn_s_setprio(0);                                     \
            _Pragma("unroll")                                                  \
            for (int n = 0; n < 4; ++n)                                        \
                bfr[n] = *(const bf16x8*)&lds[BUF][boff + (4 + n) * 1024 + gx]; \
            __builtin_amdgcn_s_barrier();                                      \
            __builtin_amdgcn_s_setprio(1);                                     \
            _Pragma("unroll")                                                  \
            for (int m = 0; m < 5; ++m)                                        \
                _Pragma("unroll")                                              \
                for (int n = 0; n < 4; ++n)                                    \
                    acc[m][4 + n] = __builtin_amdgcn_mfma_f32_16x16x32_bf16(   \
                        afr[m], bfr[n], acc[m][4 + n], 0, 0, 0);               \
            __builtin_amdgcn_s_setprio(0);                                     \
        }                                                                      \
    }

__global__ __launch_bounds__(512, 2) void gemm3_kernel(
    const unsigned short* __restrict__ simB,
    const unsigned short* __restrict__ W1T,
    const float* __restrict__ b1, const float* __restrict__ W2,
    float* __restrict__ s_pre) {
    // A: [0,20480) = 320x64, B: [20480,36864) = 256x64, per buffer (72 KB).
    __shared__ unsigned short lds[2][36864];

    const int t    = threadIdx.x;
    const int lane = t & 63;
    const int wv   = t >> 6;
    const int wr   = wv >> 1;          // 0..3  (80-row group)
    const int wc   = wv & 1;           // 0..1  (128-col group)
    const int lr   = lane & 15;
    const int g4   = lane >> 4;        // 0..3
    const int l7   = lane & 7;

    // A-panel-per-XCD pinning: same-bm blocks are i === bm (mod 32) -> same XCD.
    const int bm = blockIdx.x & 31;
    const int bn = blockIdx.x >> 5;    // 0..7
    const int m0 = bm * BM3, n0 = bn * BN3;

    // staging source (pre-swizzled granule so linear LDS dest = swizzled layout)
    const int trow = t >> 3;                       // 0..63
    const int gsrc = (t & 7) ^ (trow & 7);
    const unsigned short* gA = simB + (size_t)(m0 + trow) * KK + gsrc * 8;
    const unsigned short* gB = W1T  + (size_t)(n0 + trow) * KK + gsrc * 8;

    // swizzled ds_read offsets (elements); row&7 == lane&7 for both A and B
    const int aoff = (wr * 80 + lr) * 64;
    const int boff = 20480 + (wc * 128 + lr) * 64;
    const int gx0  = ((0 * 4 + g4) ^ l7) * 8;
    const int gx1  = ((1 * 4 + g4) ^ l7) * 8;

    f32x4 acc[5][8];
#pragma unroll
    for (int m = 0; m < 5; ++m)
#pragma unroll
        for (int n = 0; n < 8; ++n)
            acc[m][n] = (f32x4){0.f, 0.f, 0.f, 0.f};

    // prologue: stage kt=0 into buf 0 (A then B; FIFO order matters)
    STAGE_A(0, 0)
    STAGE_B(0, 0)

#pragma unroll 1
    for (int kt = 0; kt < NKT - 2; kt += 2) {
        BODY(kt,     0, "4", "5", 1)
        BODY(kt + 1, 1, "4", "5", 1)
    }
    BODY(NKT - 2, 0, "4", "5", 1)
    BODY(NKT - 1, 1, "4", "0", 0)

    // epilogue: relu(+b1), dot W2, 16-lane reduce, atomicAdd into s_pre
    float b1v[8], w2v[8];
#pragma unroll
    for (int n = 0; n < 8; ++n) {
        int col = n0 + wc * 128 + n * 16 + lr;
        b1v[n] = b1[col];
        w2v[n] = W2[col];
    }
#pragma unroll
    for (int m = 0; m < 5; ++m) {
#pragma unroll
        for (int r = 0; r < 4; ++r) {
            float rowsum = 0.f;
#pragma unroll
            for (int n = 0; n < 8; ++n) {
                float v = acc[m][n][r] + b1v[n];
                v = fmaxf(v, 0.f);
                rowsum = fmaf(v, w2v[n], rowsum);
            }
            rowsum += __shfl_xor(rowsum, 1);
            rowsum += __shfl_xor(rowsum, 2);
            rowsum += __shfl_xor(rowsum, 4);
            rowsum += __shfl_xor(rowsum, 8);
            if (lr == 0) {
                int row = m0 + wr * 80 + m * 16 + g4 * 4 + r;
                atomicAdd(&s_pre[row], rowsum);
            }
        }
    }
}

// ---------------------------------------------------------------------------
// Fallback GEMM (inline sim staging) — used only if ws too small for simB.
// ---------------------------------------------------------------------------
#define BM 128
#define BN 128
#define BK 32

__global__ __launch_bounds__(256) void gemm_kernel(
    const float* __restrict__ x0, const float* __restrict__ x1,
    const unsigned short* __restrict__ W1T,
    const float* __restrict__ b1, const float* __restrict__ W2,
    float* __restrict__ s_pre) {
    __shared__ unsigned short As[BM][BK];
    __shared__ unsigned short Bs[BN][BK];

    const int tid  = threadIdx.x;
    const int lane = tid & 63;
    const int wave = tid >> 6;
    const int wr = wave >> 1, wc = wave & 1;
    const int bm = blockIdx.x / (DD / BN);
    const int bn = blockIdx.x % (DD / BN);
    const int m0 = bm * BM, n0 = bn * BN;
    const int lr = lane & 15;
    const int lk = (lane >> 4) * 8;

    f32x4 acc[4][4];
#pragma unroll
    for (int m = 0; m < 4; ++m)
#pragma unroll
        for (int n = 0; n < 4; ++n)
            acc[m][n] = (f32x4){0.f, 0.f, 0.f, 0.f};

    for (int k0 = 0; k0 < KK; k0 += BK) {
        __syncthreads();
#pragma unroll
        for (int p = 0; p < 2; ++p) {
            int L  = tid + p * 256;
            int n  = L >> 2;
            int k8 = (L & 3) * 8;
            const unsigned short* g = &W1T[(size_t)(n0 + n) * KK + k0 + k8];
            unsigned short* l = &Bs[0][0] + (size_t)L * 8;
            __builtin_amdgcn_global_load_lds(
                (const __attribute__((address_space(1))) void*)g,
                (__attribute__((address_space(3))) void*)l, 16, 0, 0);
        }
        {
            const int f0 = k0 & (DD - 1);
            const bool second = (k0 >= DD);
            const int fc = (tid & 7) * 4;
            const float4 v0 = *(const float4*)&x0[f0 + fc];
#pragma unroll
            for (int p = 0; p < 4; ++p) {
                int row = p * 32 + (tid >> 3);
                const float4 v1 = *(const float4*)&x1[(size_t)(m0 + row) * DD + f0 + fc];
                ushort4 o;
                o.x = f2bf_rne(second ? (v0.x + v1.x) : fabsf(v0.x - v1.x));
                o.y = f2bf_rne(second ? (v0.y + v1.y) : fabsf(v0.y - v1.y));
                o.z = f2bf_rne(second ? (v0.z + v1.z) : fabsf(v0.z - v1.z));
                o.w = f2bf_rne(second ? (v0.w + v1.w) : fabsf(v0.w - v1.w));
                *(ushort4*)&As[row][fc] = o;
            }
        }
        __syncthreads();

        bf16x8 a[4], b[4];
#pragma unroll
        for (int m = 0; m < 4; ++m)
            a[m] = *(const bf16x8*)&As[wr * 64 + m * 16 + lr][lk];
#pragma unroll
        for (int n = 0; n < 4; ++n)
            b[n] = *(const bf16x8*)&Bs[wc * 64 + n * 16 + lr][lk];
#pragma unroll
        for (int m = 0; m < 4; ++m)
#pragma unroll
            for (int n = 0; n < 4; ++n)
                acc[m][n] = __builtin_amdgcn_mfma_f32_16x16x32_bf16(
                    a[m], b[n], acc[m][n], 0, 0, 0);
    }

    float b1v[4], w2v[4];
#pragma unroll
    for (int n = 0; n < 4; ++n) {
        int col = n0 + wc * 64 + n * 16 + lr;
        b1v[n] = b1[col];
        w2v[n] = W2[col];
    }
#pragma unroll
    for (int m = 0; m < 4; ++m) {
#pragma unroll
        for (int r = 0; r < 4; ++r) {
            float rowsum = 0.f;
#pragma unroll
            for (int n = 0; n < 4; ++n) {
                float v = acc[m][n][r] + b1v[n];
                v = fmaxf(v, 0.f);
                rowsum = fmaf(v, w2v[n], rowsum);
            }
            rowsum += __shfl_xor(rowsum, 1);
            rowsum += __shfl_xor(rowsum, 2);
            rowsum += __shfl_xor(rowsum, 4);
            rowsum += __shfl_xor(rowsum, 8);
            if (lr == 0) {
                int row = m0 + wr * 64 + m * 16 + (lane >> 4) * 4 + r;
                atomicAdd(&s_pre[row], rowsum);
            }
        }
    }
}

// ---------------------------------------------------------------------------
// Chunk-parallel BiLSTM. CHUNK=64, WARM=192 (worst-case contraction 0.95 ->
// boundary error ~5e-5 << 1e-2). float4-batched s_pre loads: s_pre (40 KB)
// misses L1 -> scalar per-step loads put ~200cy L2 latency on the serial
// chain; one float4 per 4 steps amortizes it. pstart/pend multiples of 4.
// ---------------------------------------------------------------------------
#define CHUNK 64
#define WARM  192
#define NCH   (SS / CHUNK)   // 160

__device__ __forceinline__ float sigf(float x) {
    return 1.f / (1.f + __expf(-x));
}
__device__ __forceinline__ float tanhfast(float x) {
    return 2.f / (1.f + __expf(-2.f * x)) - 1.f;
}

__global__ __launch_bounds__(64) void lstm_kernel(
    const float* __restrict__ s_pre,
    const float* __restrict__ Wih_f, const float* __restrict__ Whh_f,
    const float* __restrict__ bih_f, const float* __restrict__ bhh_f,
    const float* __restrict__ Wih_b, const float* __restrict__ Whh_b,
    const float* __restrict__ bih_b, const float* __restrict__ bhh_b,
    float* __restrict__ hf, float* __restrict__ hb) {
    int id = blockIdx.x * blockDim.x + threadIdx.x;
    if (id >= 2 * NCH) return;
    int dir = id / NCH;
    int ch  = id % NCH;
    const float* Wih = dir ? Wih_b : Wih_f;
    const float* Whh = dir ? Whh_b : Whh_f;
    const float* bih = dir ? bih_b : bih_f;
    const float* bhh = dir ? bhh_b : bhh_f;
    const float wi0 = Wih[0], wi1 = Wih[1], wi2 = Wih[2], wi3 = Wih[3];
    const float wh0 = Whh[0], wh1 = Whh[1], wh2 = Whh[2], wh3 = Whh[3];
    const float bb0 = bih[0] + bhh[0], bb1 = bih[1] + bhh[1];
    const float bb2 = bih[2] + bhh[2], bb3 = bih[3] + bhh[3];

    const int pout0 = ch * CHUNK;
    int pstart = pout0 - WARM; if (pstart < 0) pstart = 0;
    const int pend = pout0 + CHUNK;

    float h = 0.f, c = 0.f;
    for (int p4 = pstart; p4 < pend; p4 += 4) {
        float4 xv;
        if (dir == 0) {
            xv = *(const float4*)&s_pre[p4];
        } else {
            const float4 tv = *(const float4*)&s_pre[SS - 4 - p4];
            xv = (float4){tv.w, tv.z, tv.y, tv.x};
        }
        const bool wr_out = (p4 >= pout0);   // pout0, p4 both multiples of 4
        const float xa[4] = {xv.x, xv.y, xv.z, xv.w};
#pragma unroll
        for (int q = 0; q < 4; ++q) {
            const int p = p4 + q;
            float x  = sigf(xa[q]);
            float g0 = fmaf(wi0, x, fmaf(wh0, h, bb0));
            float g1 = fmaf(wi1, x, fmaf(wh1, h, bb1));
            float g2 = fmaf(wi2, x, fmaf(wh2, h, bb2));
            float g3 = fmaf(wi3, x, fmaf(wh3, h, bb3));
            float gi = sigf(g0);
            float gf = sigf(g1);
            float gg = tanhfast(g2);
            float go = sigf(g3);
            c = fmaf(gf, c, gi * gg);
            h = go * tanhfast(c);
            if (wr_out) {
                int s = dir ? (SS - 1 - p) : p;
                if (dir) hb[s] = h; else hf[s] = h;
            }
        }
    }
}

// ---------------------------------------------------------------------------
// Head
// ---------------------------------------------------------------------------
__global__ __launch_bounds__(256) void final_kernel(
    const float* __restrict__ hf, const float* __restrict__ hb,
    const float* __restrict__ W3, const float* __restrict__ b3,
    float* __restrict__ out) {
    int j = blockIdx.x * blockDim.x + threadIdx.x;
    if (j >= (SS * 2) / 10) return;   // 2048
    float acc = b3[0];
#pragma unroll
    for (int i = 0; i < 5; ++i) {
        acc = fmaf(hf[5 * j + i], W3[2 * i],     acc);
        acc = fmaf(hb[5 * j + i], W3[2 * i + 1], acc);
    }
    out[j] = sigf(acc);
}

// ---------------------------------------------------------------------------
extern "C" void kernel_launch(void* const* d_in, const int* in_sizes, int n_in,
                              void* d_out, int out_size, void* d_ws, size_t ws_size,
                              hipStream_t stream) {
    const float* x0    = (const float*)d_in[0];
    const float* x1    = (const float*)d_in[1];
    const float* W1    = (const float*)d_in[2];
    const float* b1    = (const float*)d_in[3];
    const float* W2    = (const float*)d_in[4];
    const float* b2    = (const float*)d_in[5];
    const float* Wih_f = (const float*)d_in[6];
    const float* Whh_f = (const float*)d_in[7];
    const float* bih_f = (const float*)d_in[8];
    const float* bhh_f = (const float*)d_in[9];
    const float* Wih_b = (const float*)d_in[10];
    const float* Whh_b = (const float*)d_in[11];
    const float* bih_b = (const float*)d_in[12];
    const float* bhh_b = (const float*)d_in[13];
    const float* W3    = (const float*)d_in[14];
    const float* b3    = (const float*)d_in[15];
    float* out = (float*)d_out;

    char* ws = (char*)d_ws;
    const size_t w1t_bytes = (size_t)KK * DD * 2;        // 16 MB
    unsigned short* W1T = (unsigned short*)ws;
    float* s_pre = (float*)(ws + w1t_bytes);             // 40 KB
    float* hf    = s_pre + SS;
    float* hb    = hf + SS;
    size_t off_sim = w1t_bytes + 3 * (size_t)SS * 4;
    off_sim = (off_sim + 255) & ~(size_t)255;
    unsigned short* simB = (unsigned short*)(ws + off_sim);
    const size_t need = off_sim + (size_t)SS * KK * 2;   // ~100.8 MB

    if (ws_size >= need) {
        prep_sim_kernel<<<(KK / 64) * (DD / 64) + SS, 256, 0, stream>>>(
            W1, b2, x0, x1, W1T, s_pre, simB);
        gemm3_kernel<<<(SS / BM3) * (DD / BN3), 512, 0, stream>>>(
            simB, W1T, b1, W2, s_pre);
    } else {
        prep_sim_kernel<<<(KK / 64) * (DD / 64), 256, 0, stream>>>(
            W1, b2, x0, x1, W1T, s_pre, simB);
        gemm_kernel<<<(SS / BM) * (DD / BN), 256, 0, stream>>>(
            x0, x1, W1T, b1, W2, s_pre);
    }
    lstm_kernel<<<(2 * NCH + 63) / 64, 64, 0, stream>>>(
        s_pre, Wih_f, Whh_f, bih_f, bhh_f, Wih_b, Whh_b, bih_b, bhh_b, hf, hb);
    final_kernel<<<((SS * 2) / 10 + 255) / 256, 256, 0, stream>>>(hf, hb, W3, b3, out);
}